// Round 1
// baseline (1793.279 us; speedup 1.0000x reference)
//
#include <hip/hip_runtime.h>
#include <hip/hip_bf16.h>

#define N_NODES 100000
#define N_EDGES 1600000
#define N_GRAPHS 512
#define NODE_DIM 64
#define GRAPH_DIM 16
#define HIDDEN 128
#define OUT_DIM 8

// ---------------- degree / norm ----------------

__global__ void k_deg(const int* __restrict__ dst, int* __restrict__ degcnt) {
    int e = blockIdx.x * blockDim.x + threadIdx.x;
    if (e < N_EDGES) atomicAdd(&degcnt[dst[e]], 1);
}

__global__ void k_dinv(const int* __restrict__ degcnt, float* __restrict__ dinv) {
    int i = blockIdx.x * blockDim.x + threadIdx.x;
    if (i < N_NODES) dinv[i] = rsqrtf((float)degcnt[i] + 1.0f);
}

__global__ void k_norm(const int* __restrict__ src, const int* __restrict__ dst,
                       const float* __restrict__ dinv, float* __restrict__ norm) {
    int e = blockIdx.x * blockDim.x + threadIdx.x;
    if (e < N_EDGES) norm[e] = dinv[src[e]] * dinv[dst[e]];
}

// ---------------- graph feature pooling (x[:,64:80]) + node counts ----------------

__global__ void k_graphstat(const float* __restrict__ x, const int* __restrict__ batch,
                            float* __restrict__ gt_sum, int* __restrict__ gcnt) {
    int gid = blockIdx.x * blockDim.x + threadIdx.x;
    if (gid >= N_NODES * GRAPH_DIM) return;
    int i = gid >> 4;          // node
    int c = gid & 15;          // channel 0..15
    int g = batch[i];
    atomicAdd(&gt_sum[g * GRAPH_DIM + c], x[(size_t)i * 80 + NODE_DIM + c]);
    if (c == 0) atomicAdd(&gcnt[g], 1);
}

// ---------------- GEMM: C[nrows x 128] = A[nrows x K (lda)] * W[K x 128] ----------------

template <int K>
__global__ void k_gemm(const float* __restrict__ A, int lda, const float* __restrict__ W,
                       float* __restrict__ C, int nrows) {
    const int TM = 8;
    __shared__ float As[TM][K];
    int row0 = blockIdx.x * TM;
    int j = threadIdx.x;  // 0..127
    for (int idx = threadIdx.x; idx < TM * K; idx += 128) {
        int m = idx / K, k = idx % K;
        int r = row0 + m;
        As[m][k] = (r < nrows) ? A[(size_t)r * lda + k] : 0.0f;
    }
    __syncthreads();
    float acc[TM];
#pragma unroll
    for (int m = 0; m < TM; m++) acc[m] = 0.0f;
    for (int k = 0; k < K; k++) {
        float w = W[k * 128 + j];
#pragma unroll
        for (int m = 0; m < TM; m++) acc[m] += As[m][k] * w;
    }
#pragma unroll
    for (int m = 0; m < TM; m++) {
        int r = row0 + m;
        if (r < nrows) C[(size_t)r * 128 + j] = acc[m];
    }
}

// ---------------- edge scatter: out[dst] += norm * t[src], one thread per (edge, ch) ----------------

__global__ void k_scatter(const int* __restrict__ src, const int* __restrict__ dst,
                          const float* __restrict__ norm, const float* __restrict__ t,
                          float* __restrict__ out) {
    long long gid = (long long)blockIdx.x * blockDim.x + threadIdx.x;
    if (gid >= (long long)N_EDGES * 128) return;
    int e = (int)(gid >> 7);
    int c = (int)(gid & 127);
    int s = src[e], d = dst[e];
    float v = norm[e] * t[(size_t)s * 128 + c];
    atomicAdd(&out[(size_t)d * 128 + c], v);
}

// ---------------- self-loop + bias (+ optional relu), in-place on out ----------------

template <bool RELU>
__global__ void k_self(float* __restrict__ out, const float* __restrict__ t,
                       const float* __restrict__ dinv, const float* __restrict__ b) {
    long long gid = (long long)blockIdx.x * blockDim.x + threadIdx.x;
    if (gid >= (long long)N_NODES * 128) return;
    int i = (int)(gid >> 7);
    int c = (int)(gid & 127);
    float di = dinv[i];
    float v = out[(size_t)i * 128 + c] + di * di * t[(size_t)i * 128 + c] + b[c];
    if (RELU) v = fmaxf(v, 0.0f);
    out[(size_t)i * 128 + c] = v;
}

// ---------------- mean pool of h2 ----------------

__global__ void k_pool(const float* __restrict__ h, const int* __restrict__ batch,
                       float* __restrict__ gsum) {
    long long gid = (long long)blockIdx.x * blockDim.x + threadIdx.x;
    if (gid >= (long long)N_NODES * 128) return;
    int i = (int)(gid >> 7);
    int c = (int)(gid & 127);
    atomicAdd(&gsum[batch[i] * 128 + c], h[(size_t)i * 128 + c]);
}

// ---------------- final MLP per graph ----------------

__global__ void k_mlp(const float* __restrict__ gsum2, const float* __restrict__ gt_sum,
                      const int* __restrict__ gcnt, const float* __restrict__ Wm1,
                      const float* __restrict__ bm1, const float* __restrict__ Wm2,
                      const float* __restrict__ bm2, float* __restrict__ out) {
    __shared__ float g144[HIDDEN + GRAPH_DIM];
    __shared__ float sm[HIDDEN];
    int b = blockIdx.x;
    int j = threadIdx.x;  // 0..127
    float cnt = fmaxf((float)gcnt[b], 1.0f);
    float inv = 1.0f / cnt;
    g144[j] = gsum2[b * 128 + j] * inv;
    if (j < GRAPH_DIM) g144[128 + j] = gt_sum[b * GRAPH_DIM + j] * inv;
    __syncthreads();
    float acc = bm1[j];
    for (int k = 0; k < HIDDEN + GRAPH_DIM; k++) acc += g144[k] * Wm1[k * 128 + j];
    sm[j] = fmaxf(acc, 0.0f);
    __syncthreads();
    if (j < OUT_DIM) {
        float o = bm2[j];
        for (int k = 0; k < 128; k++) o += sm[k] * Wm2[k * OUT_DIM + j];
        out[b * OUT_DIM + j] = o;
    }
}

extern "C" void kernel_launch(void* const* d_in, const int* in_sizes, int n_in,
                              void* d_out, int out_size, void* d_ws, size_t ws_size,
                              hipStream_t stream) {
    const float* x    = (const float*)d_in[0];
    const int*   edge = (const int*)d_in[1];
    const int*   src  = edge;
    const int*   dst  = edge + N_EDGES;
    const int*   batch= (const int*)d_in[2];
    const float* W1   = (const float*)d_in[3];
    const float* b1   = (const float*)d_in[4];
    const float* W2   = (const float*)d_in[5];
    const float* b2   = (const float*)d_in[6];
    const float* Wm1  = (const float*)d_in[7];
    const float* bm1  = (const float*)d_in[8];
    const float* Wm2  = (const float*)d_in[9];
    const float* bm2  = (const float*)d_in[10];
    float* out = (float*)d_out;

    // workspace layout (~110 MB)
    char* ws = (char*)d_ws;
    const size_t SZ = (size_t)N_NODES * 128 * 4;  // 51.2 MB
    float* A      = (float*)(ws);                       // t (GEMM output)
    float* B      = (float*)(ws + SZ);                  // scatter accum / h
    char*  p      = ws + 2 * SZ;
    float* dinv   = (float*)p;            p += (size_t)N_NODES * 4;
    int*   degcnt = (int*)p;              p += (size_t)N_NODES * 4;
    float* norm   = (float*)p;            p += (size_t)N_EDGES * 4;
    float* gt_sum = (float*)p;            p += (size_t)N_GRAPHS * GRAPH_DIM * 4;
    int*   gcnt   = (int*)p;              p += (size_t)N_GRAPHS * 4;
    float* gsum2  = (float*)p;            p += (size_t)N_GRAPHS * 128 * 4;

    // zero-init accumulators
    hipMemsetAsync(degcnt, 0, (size_t)N_NODES * 4, stream);
    hipMemsetAsync(gt_sum, 0, (size_t)N_GRAPHS * GRAPH_DIM * 4, stream);
    hipMemsetAsync(gcnt,   0, (size_t)N_GRAPHS * 4, stream);
    hipMemsetAsync(gsum2,  0, (size_t)N_GRAPHS * 128 * 4, stream);
    hipMemsetAsync(B,      0, SZ, stream);

    const int BS = 256;
    // degrees & norms
    k_deg<<<(N_EDGES + BS - 1) / BS, BS, 0, stream>>>(dst, degcnt);
    k_dinv<<<(N_NODES + BS - 1) / BS, BS, 0, stream>>>(degcnt, dinv);
    k_norm<<<(N_EDGES + BS - 1) / BS, BS, 0, stream>>>(src, dst, dinv, norm);
    // graph_t pooling + counts
    k_graphstat<<<(N_NODES * GRAPH_DIM + BS - 1) / BS, BS, 0, stream>>>(x, batch, gt_sum, gcnt);

    // conv1: t1 = x[:, :64] @ W1
    k_gemm<64><<<(N_NODES + 7) / 8, 128, 0, stream>>>(x, 80, W1, A, N_NODES);
    k_scatter<<<(int)(((long long)N_EDGES * 128 + BS - 1) / BS), BS, 0, stream>>>(src, dst, norm, A, B);
    k_self<true><<<(int)(((long long)N_NODES * 128 + BS - 1) / BS), BS, 0, stream>>>(B, A, dinv, b1);

    // conv2: t2 = h1 @ W2
    k_gemm<128><<<(N_NODES + 7) / 8, 128, 0, stream>>>(B, 128, W2, A, N_NODES);
    hipMemsetAsync(B, 0, SZ, stream);
    k_scatter<<<(int)(((long long)N_EDGES * 128 + BS - 1) / BS), BS, 0, stream>>>(src, dst, norm, A, B);
    k_self<false><<<(int)(((long long)N_NODES * 128 + BS - 1) / BS), BS, 0, stream>>>(B, A, dinv, b2);

    // pool h2
    k_pool<<<(int)(((long long)N_NODES * 128 + BS - 1) / BS), BS, 0, stream>>>(B, batch, gsum2);

    // final MLP
    k_mlp<<<N_GRAPHS, 128, 0, stream>>>(gsum2, gt_sum, gcnt, Wm1, bm1, Wm2, bm2, out);
}

// Round 2
// 585.775 us; speedup vs baseline: 3.0614x; 3.0614x over previous
//
#include <hip/hip_runtime.h>
#include <hip/hip_bf16.h>

#define N_NODES 100000
#define N_EDGES 1600000
#define N_GRAPHS 512
#define NODE_DIM 64
#define GRAPH_DIM 16
#define HIDDEN 128
#define OUT_DIM 8

// ---------------- degree ----------------

__global__ void k_deg(const int* __restrict__ dst, int* __restrict__ degcnt) {
    int e = blockIdx.x * blockDim.x + threadIdx.x;
    if (e < N_EDGES) atomicAdd(&degcnt[dst[e]], 1);
}

__global__ void k_dinv(const int* __restrict__ degcnt, float* __restrict__ dinv) {
    int i = blockIdx.x * blockDim.x + threadIdx.x;
    if (i < N_NODES) dinv[i] = rsqrtf((float)degcnt[i] + 1.0f);
}

// ---------------- prefix scan over degcnt -> row_start ----------------

__global__ void k_blocksum(const int* __restrict__ cnt, int* __restrict__ bsum) {
    __shared__ int s[256];
    int i = blockIdx.x * 256 + threadIdx.x;
    s[threadIdx.x] = (i < N_NODES) ? cnt[i] : 0;
    __syncthreads();
    for (int o = 128; o > 0; o >>= 1) {
        if (threadIdx.x < o) s[threadIdx.x] += s[threadIdx.x + o];
        __syncthreads();
    }
    if (threadIdx.x == 0) bsum[blockIdx.x] = s[0];
}

__global__ void k_scanb(const int* __restrict__ bsum, int* __restrict__ bofs, int nb) {
    if (threadIdx.x == 0) {
        int a = 0;
        for (int i = 0; i < nb; i++) { bofs[i] = a; a += bsum[i]; }
    }
}

__global__ void k_rowstart(const int* __restrict__ cnt, const int* __restrict__ bofs,
                           int* __restrict__ row_start) {
    __shared__ int s[256];
    int i = blockIdx.x * 256 + threadIdx.x;
    int v = (i < N_NODES) ? cnt[i] : 0;
    s[threadIdx.x] = v;
    __syncthreads();
    for (int o = 1; o < 256; o <<= 1) {
        int t = (threadIdx.x >= o) ? s[threadIdx.x - o] : 0;
        __syncthreads();
        s[threadIdx.x] += t;
        __syncthreads();
    }
    if (i < N_NODES) row_start[i] = bofs[blockIdx.x] + s[threadIdx.x] - v;  // exclusive
}

// ---------------- CSR fill (by dst), entry = {src, norm} ----------------

__global__ void k_fill(const int* __restrict__ src, const int* __restrict__ dst,
                       const float* __restrict__ dinv, const int* __restrict__ row_start,
                       int* __restrict__ cnt2, int2* __restrict__ csr) {
    int e = blockIdx.x * blockDim.x + threadIdx.x;
    if (e >= N_EDGES) return;
    int s = src[e], d = dst[e];
    float w = dinv[s] * dinv[d];
    int pos = row_start[d] + atomicAdd(&cnt2[d], 1);
    csr[pos] = make_int2(s, __float_as_int(w));
}

// ---------------- graph feature pooling (x[:,64:80]) with sorted-batch flush ----------------

__global__ void k_graphstat(const float* __restrict__ x, const int* __restrict__ batch,
                            float* __restrict__ gt_sum) {
    int c = threadIdx.x & 15;
    int sub = threadIdx.x >> 4;  // 0..7
    int i0 = blockIdx.x * 64;
    int iend = min(i0 + 64, N_NODES);
    float acc = 0.0f;
    int g = -1;
    for (int i = i0 + sub; i < iend; i += 8) {
        int bi = batch[i];
        if (bi != g) {
            if (g >= 0) atomicAdd(&gt_sum[g * GRAPH_DIM + c], acc);
            acc = 0.0f; g = bi;
        }
        acc += x[(size_t)i * 80 + NODE_DIM + c];
    }
    if (g >= 0) atomicAdd(&gt_sum[g * GRAPH_DIM + c], acc);
}

// ---------------- per-graph node counts via binary search (batch sorted) ----------------

__global__ void k_gcnt(const int* __restrict__ batch, int* __restrict__ gcnt) {
    int g = blockIdx.x * blockDim.x + threadIdx.x;
    if (g >= N_GRAPHS) return;
    int lo = 0, hi = N_NODES;
    while (lo < hi) { int m = (lo + hi) >> 1; if (batch[m] < g) lo = m + 1; else hi = m; }
    int a = lo;
    lo = 0; hi = N_NODES;
    while (lo < hi) { int m = (lo + hi) >> 1; if (batch[m] < g + 1) lo = m + 1; else hi = m; }
    gcnt[g] = lo - a;
}

// ---------------- GEMM: C[nrows x 128] = A[nrows x K (lda)] * W[K x 128] ----------------

template <int K>
__global__ void k_gemm(const float* __restrict__ A, int lda, const float* __restrict__ W,
                       float* __restrict__ C, int nrows) {
    const int TM = 8;
    __shared__ float As[TM][K];
    int row0 = blockIdx.x * TM;
    int j = threadIdx.x;  // 0..127
    for (int idx = threadIdx.x; idx < TM * K; idx += 128) {
        int m = idx / K, k = idx % K;
        int r = row0 + m;
        As[m][k] = (r < nrows) ? A[(size_t)r * lda + k] : 0.0f;
    }
    __syncthreads();
    float acc[TM];
#pragma unroll
    for (int m = 0; m < TM; m++) acc[m] = 0.0f;
    for (int k = 0; k < K; k++) {
        float w = W[k * 128 + j];
#pragma unroll
        for (int m = 0; m < TM; m++) acc[m] += As[m][k] * w;
    }
#pragma unroll
    for (int m = 0; m < TM; m++) {
        int r = row0 + m;
        if (r < nrows) C[(size_t)r * 128 + j] = acc[m];
    }
}

// ---------------- gather GCN aggregation + self loop + bias (+relu) ----------------

template <bool RELU>
__global__ void k_gather(const int2* __restrict__ csr, const int* __restrict__ row_start,
                         const int* __restrict__ deg, const float* __restrict__ dinv,
                         const float* __restrict__ t, const float* __restrict__ bias,
                         float* __restrict__ out) {
    int node = blockIdx.x * 4 + (threadIdx.x >> 6);
    int lane = threadIdx.x & 63;
    if (node >= N_NODES) return;
    const float2* t2 = (const float2*)t;
    int rs = row_start[node];
    int dn = deg[node];
    float2 a0 = make_float2(0.f, 0.f), a1 = make_float2(0.f, 0.f);
    int k = 0;
    for (; k + 2 <= dn; k += 2) {
        int2 e0 = csr[rs + k];
        int2 e1 = csr[rs + k + 1];
        float w0 = __int_as_float(e0.y), w1 = __int_as_float(e1.y);
        float2 v0 = t2[(size_t)e0.x * 64 + lane];
        float2 v1 = t2[(size_t)e1.x * 64 + lane];
        a0.x += w0 * v0.x; a0.y += w0 * v0.y;
        a1.x += w1 * v1.x; a1.y += w1 * v1.y;
    }
    if (k < dn) {
        int2 e0 = csr[rs + k];
        float w0 = __int_as_float(e0.y);
        float2 v0 = t2[(size_t)e0.x * 64 + lane];
        a0.x += w0 * v0.x; a0.y += w0 * v0.y;
    }
    float di = dinv[node];
    float dd = di * di;
    float2 sv = t2[(size_t)node * 64 + lane];
    float2 bb = ((const float2*)bias)[lane];
    float ox = a0.x + a1.x + dd * sv.x + bb.x;
    float oy = a0.y + a1.y + dd * sv.y + bb.y;
    if (RELU) { ox = fmaxf(ox, 0.f); oy = fmaxf(oy, 0.f); }
    ((float2*)out)[(size_t)node * 64 + lane] = make_float2(ox, oy);
}

// ---------------- mean pool of h2 with sorted-batch flush ----------------

__global__ void k_pool(const float* __restrict__ h, const int* __restrict__ batch,
                       float* __restrict__ gsum) {
    int c = threadIdx.x;  // 0..127
    int i0 = blockIdx.x * 64;
    int iend = min(i0 + 64, N_NODES);
    if (i0 >= N_NODES) return;
    float acc = 0.0f;
    int g = batch[i0];
    for (int i = i0; i < iend; i++) {
        int bi = batch[i];
        if (bi != g) { atomicAdd(&gsum[g * 128 + c], acc); acc = 0.0f; g = bi; }
        acc += h[(size_t)i * 128 + c];
    }
    atomicAdd(&gsum[g * 128 + c], acc);
}

// ---------------- final MLP per graph ----------------

__global__ void k_mlp(const float* __restrict__ gsum2, const float* __restrict__ gt_sum,
                      const int* __restrict__ gcnt, const float* __restrict__ Wm1,
                      const float* __restrict__ bm1, const float* __restrict__ Wm2,
                      const float* __restrict__ bm2, float* __restrict__ out) {
    __shared__ float g144[HIDDEN + GRAPH_DIM];
    __shared__ float sm[HIDDEN];
    int b = blockIdx.x;
    int j = threadIdx.x;  // 0..127
    float cnt = fmaxf((float)gcnt[b], 1.0f);
    float inv = 1.0f / cnt;
    g144[j] = gsum2[b * 128 + j] * inv;
    if (j < GRAPH_DIM) g144[128 + j] = gt_sum[b * GRAPH_DIM + j] * inv;
    __syncthreads();
    float acc = bm1[j];
    for (int k = 0; k < HIDDEN + GRAPH_DIM; k++) acc += g144[k] * Wm1[k * 128 + j];
    sm[j] = fmaxf(acc, 0.0f);
    __syncthreads();
    if (j < OUT_DIM) {
        float o = bm2[j];
        for (int k = 0; k < 128; k++) o += sm[k] * Wm2[k * OUT_DIM + j];
        out[b * OUT_DIM + j] = o;
    }
}

extern "C" void kernel_launch(void* const* d_in, const int* in_sizes, int n_in,
                              void* d_out, int out_size, void* d_ws, size_t ws_size,
                              hipStream_t stream) {
    const float* x    = (const float*)d_in[0];
    const int*   edge = (const int*)d_in[1];
    const int*   src  = edge;
    const int*   dst  = edge + N_EDGES;
    const int*   batch= (const int*)d_in[2];
    const float* W1   = (const float*)d_in[3];
    const float* b1   = (const float*)d_in[4];
    const float* W2   = (const float*)d_in[5];
    const float* b2   = (const float*)d_in[6];
    const float* Wm1  = (const float*)d_in[7];
    const float* bm1  = (const float*)d_in[8];
    const float* Wm2  = (const float*)d_in[9];
    const float* bm2  = (const float*)d_in[10];
    float* out = (float*)d_out;

    // workspace layout (~130 MB)
    char* ws = (char*)d_ws;
    const size_t SZ = (size_t)N_NODES * 128 * 4;  // 51.2 MB
    float* A        = (float*)(ws);               // t (GEMM output)
    float* B        = (float*)(ws + SZ);          // h (gather output)
    char*  p        = ws + 2 * SZ;
    int2*  csr      = (int2*)p;      p += (size_t)N_EDGES * 8;       // 12.8 MB
    float* dinv     = (float*)p;     p += (size_t)N_NODES * 4;
    int*   degcnt   = (int*)p;       p += (size_t)N_NODES * 4;
    int*   row_start= (int*)p;       p += (size_t)N_NODES * 4;
    int*   cnt2     = (int*)p;       p += (size_t)N_NODES * 4;
    int*   bsum     = (int*)p;       p += 512 * 4;
    int*   bofs     = (int*)p;       p += 512 * 4;
    float* gt_sum   = (float*)p;     p += (size_t)N_GRAPHS * GRAPH_DIM * 4;
    int*   gcnt     = (int*)p;       p += (size_t)N_GRAPHS * 4;
    float* gsum2    = (float*)p;     p += (size_t)N_GRAPHS * 128 * 4;

    const int NB_SCAN = (N_NODES + 255) / 256;  // 391

    hipMemsetAsync(degcnt, 0, (size_t)N_NODES * 4, stream);
    hipMemsetAsync(cnt2,   0, (size_t)N_NODES * 4, stream);
    hipMemsetAsync(gt_sum, 0, (size_t)N_GRAPHS * GRAPH_DIM * 4, stream);
    hipMemsetAsync(gsum2,  0, (size_t)N_GRAPHS * 128 * 4, stream);

    const int BS = 256;
    // degrees, dinv, CSR
    k_deg<<<(N_EDGES + BS - 1) / BS, BS, 0, stream>>>(dst, degcnt);
    k_dinv<<<(N_NODES + BS - 1) / BS, BS, 0, stream>>>(degcnt, dinv);
    k_blocksum<<<NB_SCAN, 256, 0, stream>>>(degcnt, bsum);
    k_scanb<<<1, 64, 0, stream>>>(bsum, bofs, NB_SCAN);
    k_rowstart<<<NB_SCAN, 256, 0, stream>>>(degcnt, bofs, row_start);
    k_fill<<<(N_EDGES + BS - 1) / BS, BS, 0, stream>>>(src, dst, dinv, row_start, cnt2, csr);

    // graph_t pooling + counts
    k_graphstat<<<(N_NODES + 63) / 64, 128, 0, stream>>>(x, batch, gt_sum);
    k_gcnt<<<(N_GRAPHS + 63) / 64, 64, 0, stream>>>(batch, gcnt);

    // conv1: t1 = x[:, :64] @ W1 ; h1 = aggregate + relu
    k_gemm<64><<<(N_NODES + 7) / 8, 128, 0, stream>>>(x, 80, W1, A, N_NODES);
    k_gather<true><<<(N_NODES + 3) / 4, 256, 0, stream>>>(csr, row_start, degcnt, dinv, A, b1, B);

    // conv2: t2 = h1 @ W2 ; h2 = aggregate
    k_gemm<128><<<(N_NODES + 7) / 8, 128, 0, stream>>>(B, 128, W2, A, N_NODES);
    k_gather<false><<<(N_NODES + 3) / 4, 256, 0, stream>>>(csr, row_start, degcnt, dinv, A, b2, B);

    // pool h2
    k_pool<<<(N_NODES + 63) / 64, 128, 0, stream>>>(B, batch, gsum2);

    // final MLP
    k_mlp<<<N_GRAPHS, 128, 0, stream>>>(gsum2, gt_sum, gcnt, Wm1, bm1, Wm2, bm2, out);
}

// Round 3
// 483.099 us; speedup vs baseline: 3.7120x; 1.2125x over previous
//
#include <hip/hip_runtime.h>
#include <hip/hip_bf16.h>

#define N_NODES 100000
#define N_EDGES 1600000
#define N_GRAPHS 512
#define NODE_DIM 64
#define GRAPH_DIM 16
#define HIDDEN 128
#define OUT_DIM 8

// ---------------- degree ----------------

__global__ void k_deg(const int* __restrict__ dst, int* __restrict__ degcnt) {
    int e = blockIdx.x * blockDim.x + threadIdx.x;
    if (e < N_EDGES) atomicAdd(&degcnt[dst[e]], 1);
}

__global__ void k_dinv(const int* __restrict__ degcnt, float* __restrict__ dinv) {
    int i = blockIdx.x * blockDim.x + threadIdx.x;
    if (i < N_NODES) dinv[i] = rsqrtf((float)degcnt[i] + 1.0f);
}

// ---------------- prefix scan over degcnt -> row_start (exclusive) ----------------

__global__ void k_blocksum(const int* __restrict__ cnt, int* __restrict__ bsum) {
    __shared__ int s[256];
    int i = blockIdx.x * 256 + threadIdx.x;
    s[threadIdx.x] = (i < N_NODES) ? cnt[i] : 0;
    __syncthreads();
    for (int o = 128; o > 0; o >>= 1) {
        if (threadIdx.x < o) s[threadIdx.x] += s[threadIdx.x + o];
        __syncthreads();
    }
    if (threadIdx.x == 0) bsum[blockIdx.x] = s[0];
}

__global__ void k_scanb(const int* __restrict__ bsum, int* __restrict__ bofs, int nb) {
    if (threadIdx.x == 0) {
        int a = 0;
        for (int i = 0; i < nb; i++) { bofs[i] = a; a += bsum[i]; }
    }
}

__global__ void k_rowstart(const int* __restrict__ cnt, const int* __restrict__ bofs,
                           int* __restrict__ row_start) {
    __shared__ int s[256];
    int i = blockIdx.x * 256 + threadIdx.x;
    int v = (i < N_NODES) ? cnt[i] : 0;
    s[threadIdx.x] = v;
    __syncthreads();
    for (int o = 1; o < 256; o <<= 1) {
        int t = (threadIdx.x >= o) ? s[threadIdx.x - o] : 0;
        __syncthreads();
        s[threadIdx.x] += t;
        __syncthreads();
    }
    if (i < N_NODES) row_start[i] = bofs[blockIdx.x] + s[threadIdx.x] - v;  // exclusive
}

// ---------------- CSR fill (by dst), entry = src; consumes degcnt via atomicSub ----------------

__global__ void k_fill(const int* __restrict__ src, const int* __restrict__ dst,
                       const int* __restrict__ row_start, int* __restrict__ degcnt,
                       int* __restrict__ csr) {
    int e = blockIdx.x * blockDim.x + threadIdx.x;
    if (e >= N_EDGES) return;
    int d = dst[e];
    int pos = row_start[d] + atomicSub(&degcnt[d], 1) - 1;
    csr[pos] = src[e];
}

// ---------------- graph feature pooling (x[:,64:80]) with sorted-batch flush ----------------

__global__ void k_graphstat(const float* __restrict__ x, const int* __restrict__ batch,
                            float* __restrict__ gt_sum) {
    int c = threadIdx.x & 15;
    int sub = threadIdx.x >> 4;  // 0..7
    int i0 = blockIdx.x * 64;
    int iend = min(i0 + 64, N_NODES);
    float acc = 0.0f;
    int g = -1;
    for (int i = i0 + sub; i < iend; i += 8) {
        int bi = batch[i];
        if (bi != g) {
            if (g >= 0) atomicAdd(&gt_sum[g * GRAPH_DIM + c], acc);
            acc = 0.0f; g = bi;
        }
        acc += x[(size_t)i * 80 + NODE_DIM + c];
    }
    if (g >= 0) atomicAdd(&gt_sum[g * GRAPH_DIM + c], acc);
}

// ---------------- per-graph node counts via binary search (batch sorted) ----------------

__global__ void k_gcnt(const int* __restrict__ batch, int* __restrict__ gcnt) {
    int g = blockIdx.x * blockDim.x + threadIdx.x;
    if (g >= N_GRAPHS) return;
    int lo = 0, hi = N_NODES;
    while (lo < hi) { int m = (lo + hi) >> 1; if (batch[m] < g) lo = m + 1; else hi = m; }
    int a = lo;
    lo = 0; hi = N_NODES;
    while (lo < hi) { int m = (lo + hi) >> 1; if (batch[m] < g + 1) lo = m + 1; else hi = m; }
    gcnt[g] = lo - a;
}

// ---------------- gather1: z = (A_hat X)[:, :64], X row-stride 80 ----------------

__global__ void k_gather1(const int* __restrict__ csr, const int* __restrict__ row_start,
                          const float* __restrict__ dinv, const float* __restrict__ x,
                          float* __restrict__ z) {
    int node = blockIdx.x * 4 + (threadIdx.x >> 6);
    int lane = threadIdx.x & 63;
    int rs = row_start[node];
    int re = (node == N_NODES - 1) ? N_EDGES : row_start[node + 1];
    float di = dinv[node];
    float a0 = 0.f, a1 = 0.f, a2 = 0.f, a3 = 0.f;
    int k = rs;
    for (; k + 4 <= re; k += 4) {
        int s0 = csr[k], s1 = csr[k + 1], s2 = csr[k + 2], s3 = csr[k + 3];
        float w0 = dinv[s0] * di, w1 = dinv[s1] * di, w2 = dinv[s2] * di, w3 = dinv[s3] * di;
        a0 += w0 * x[(size_t)s0 * 80 + lane];
        a1 += w1 * x[(size_t)s1 * 80 + lane];
        a2 += w2 * x[(size_t)s2 * 80 + lane];
        a3 += w3 * x[(size_t)s3 * 80 + lane];
    }
    for (; k < re; k++) {
        int s0 = csr[k];
        a0 += dinv[s0] * di * x[(size_t)s0 * 80 + lane];
    }
    float v = a0 + a1 + a2 + a3 + di * di * x[(size_t)node * 80 + lane];
    z[(size_t)node * 64 + lane] = v;
}

// ---------------- GEMM: C[nrows x 128] = A[nrows x K] * W[K x 128] + bias (+relu) ----------------

template <int K, bool RELU>
__global__ void k_gemm(const float* __restrict__ A, const float* __restrict__ W,
                       const float* __restrict__ bias, float* __restrict__ C, int nrows) {
    const int TM = 8;
    __shared__ float As[TM][K];
    int row0 = blockIdx.x * TM;
    int j = threadIdx.x;  // 0..127
    for (int idx = threadIdx.x; idx < TM * K; idx += 128) {
        int m = idx / K, k = idx % K;
        int r = row0 + m;
        As[m][k] = (r < nrows) ? A[(size_t)r * K + k] : 0.0f;
    }
    __syncthreads();
    float acc[TM];
#pragma unroll
    for (int m = 0; m < TM; m++) acc[m] = 0.0f;
    for (int k = 0; k < K; k++) {
        float w = W[k * 128 + j];
#pragma unroll
        for (int m = 0; m < TM; m++) acc[m] += As[m][k] * w;
    }
    float b = bias[j];
#pragma unroll
    for (int m = 0; m < TM; m++) {
        int r = row0 + m;
        if (r < nrows) {
            float v = acc[m] + b;
            if (RELU) v = fmaxf(v, 0.0f);
            C[(size_t)r * 128 + j] = v;
        }
    }
}

// ---------------- gather2 + fused mean-pool numerator: gsum2[g] += (A_hat h1)[node] ----------------

__global__ void k_gather2(const int* __restrict__ csr, const int* __restrict__ row_start,
                          const float* __restrict__ dinv, const float* __restrict__ h,
                          const int* __restrict__ batch, float* __restrict__ gsum2) {
    __shared__ float2 red[4][64];
    int w = threadIdx.x >> 6;
    int node = blockIdx.x * 4 + w;
    int lane = threadIdx.x & 63;
    const float2* h2 = (const float2*)h;
    int rs = row_start[node];
    int re = (node == N_NODES - 1) ? N_EDGES : row_start[node + 1];
    float di = dinv[node];
    float2 a0 = {0.f, 0.f}, a1 = {0.f, 0.f}, a2 = {0.f, 0.f}, a3 = {0.f, 0.f};
    int k = rs;
    for (; k + 4 <= re; k += 4) {
        int s0 = csr[k], s1 = csr[k + 1], s2 = csr[k + 2], s3 = csr[k + 3];
        float w0 = dinv[s0] * di, w1 = dinv[s1] * di, w2 = dinv[s2] * di, w3 = dinv[s3] * di;
        float2 v0 = h2[(size_t)s0 * 64 + lane];
        float2 v1 = h2[(size_t)s1 * 64 + lane];
        float2 v2 = h2[(size_t)s2 * 64 + lane];
        float2 v3 = h2[(size_t)s3 * 64 + lane];
        a0.x += w0 * v0.x; a0.y += w0 * v0.y;
        a1.x += w1 * v1.x; a1.y += w1 * v1.y;
        a2.x += w2 * v2.x; a2.y += w2 * v2.y;
        a3.x += w3 * v3.x; a3.y += w3 * v3.y;
    }
    for (; k < re; k++) {
        int s0 = csr[k];
        float w0 = dinv[s0] * di;
        float2 v0 = h2[(size_t)s0 * 64 + lane];
        a0.x += w0 * v0.x; a0.y += w0 * v0.y;
    }
    float2 sv = h2[(size_t)node * 64 + lane];
    float dd = di * di;
    float2 r;
    r.x = a0.x + a1.x + a2.x + a3.x + dd * sv.x;
    r.y = a0.y + a1.y + a2.y + a3.y + dd * sv.y;
    red[w][lane] = r;
    __syncthreads();
    int g0 = batch[blockIdx.x * 4];
    int g3 = batch[blockIdx.x * 4 + 3];
    if (g0 == g3) {
        if (w == 0) {
            float sx = red[0][lane].x + red[1][lane].x + red[2][lane].x + red[3][lane].x;
            float sy = red[0][lane].y + red[1][lane].y + red[2][lane].y + red[3][lane].y;
            atomicAdd(&gsum2[g0 * 128 + 2 * lane], sx);
            atomicAdd(&gsum2[g0 * 128 + 2 * lane + 1], sy);
        }
    } else {
        int g = batch[node];
        atomicAdd(&gsum2[g * 128 + 2 * lane], r.x);
        atomicAdd(&gsum2[g * 128 + 2 * lane + 1], r.y);
    }
}

// ---------------- final: z = mean2 @ W2 + b2 ; g=[z, gt_mean]; MLP ----------------

__global__ void k_mlp(const float* __restrict__ gsum2, const float* __restrict__ gt_sum,
                      const int* __restrict__ gcnt, const float* __restrict__ W2,
                      const float* __restrict__ b2, const float* __restrict__ Wm1,
                      const float* __restrict__ bm1, const float* __restrict__ Wm2,
                      const float* __restrict__ bm2, float* __restrict__ out) {
    __shared__ float srow[HIDDEN];
    __shared__ float g144[HIDDEN + GRAPH_DIM];
    __shared__ float sm[HIDDEN];
    int b = blockIdx.x;
    int j = threadIdx.x;  // 0..127
    float inv = 1.0f / fmaxf((float)gcnt[b], 1.0f);
    srow[j] = gsum2[b * 128 + j] * inv;
    if (j < GRAPH_DIM) g144[128 + j] = gt_sum[b * GRAPH_DIM + j] * inv;
    __syncthreads();
    float z = b2[j];
    for (int k = 0; k < 128; k++) z += srow[k] * W2[k * 128 + j];
    g144[j] = z;
    __syncthreads();
    float acc = bm1[j];
    for (int k = 0; k < HIDDEN + GRAPH_DIM; k++) acc += g144[k] * Wm1[k * 128 + j];
    sm[j] = fmaxf(acc, 0.0f);
    __syncthreads();
    if (j < OUT_DIM) {
        float o = bm2[j];
        for (int k = 0; k < 128; k++) o += sm[k] * Wm2[k * OUT_DIM + j];
        out[b * OUT_DIM + j] = o;
    }
}

extern "C" void kernel_launch(void* const* d_in, const int* in_sizes, int n_in,
                              void* d_out, int out_size, void* d_ws, size_t ws_size,
                              hipStream_t stream) {
    const float* x    = (const float*)d_in[0];
    const int*   edge = (const int*)d_in[1];
    const int*   src  = edge;
    const int*   dst  = edge + N_EDGES;
    const int*   batch= (const int*)d_in[2];
    const float* W1   = (const float*)d_in[3];
    const float* b1   = (const float*)d_in[4];
    const float* W2   = (const float*)d_in[5];
    const float* b2   = (const float*)d_in[6];
    const float* Wm1  = (const float*)d_in[7];
    const float* bm1  = (const float*)d_in[8];
    const float* Wm2  = (const float*)d_in[9];
    const float* bm2  = (const float*)d_in[10];
    float* out = (float*)d_out;

    // workspace layout (~85 MB)
    char* ws = (char*)d_ws;
    float* A        = (float*)ws;                                   // z1: 100K x 64 (25.6 MB)
    float* B        = (float*)(ws + (size_t)N_NODES * 64 * 4);      // h1: 100K x 128 (51.2 MB)
    char*  p        = ws + (size_t)N_NODES * (64 + 128) * 4;
    int*   csr      = (int*)p;       p += (size_t)N_EDGES * 4;      // 6.4 MB
    float* dinv     = (float*)p;     p += (size_t)N_NODES * 4;
    int*   degcnt   = (int*)p;       p += (size_t)N_NODES * 4;
    int*   row_start= (int*)p;       p += (size_t)N_NODES * 4;
    int*   bsum     = (int*)p;       p += 512 * 4;
    int*   bofs     = (int*)p;       p += 512 * 4;
    float* gt_sum   = (float*)p;     p += (size_t)N_GRAPHS * GRAPH_DIM * 4;
    int*   gcnt     = (int*)p;       p += (size_t)N_GRAPHS * 4;
    float* gsum2    = (float*)p;     p += (size_t)N_GRAPHS * 128 * 4;

    const int NB_SCAN = (N_NODES + 255) / 256;  // 391

    hipMemsetAsync(degcnt, 0, (size_t)N_NODES * 4, stream);
    hipMemsetAsync(gt_sum, 0, (size_t)N_GRAPHS * GRAPH_DIM * 4, stream);
    hipMemsetAsync(gsum2,  0, (size_t)N_GRAPHS * 128 * 4, stream);

    const int BS = 256;
    // degrees, dinv, CSR
    k_deg<<<(N_EDGES + BS - 1) / BS, BS, 0, stream>>>(dst, degcnt);
    k_dinv<<<(N_NODES + BS - 1) / BS, BS, 0, stream>>>(degcnt, dinv);
    k_blocksum<<<NB_SCAN, 256, 0, stream>>>(degcnt, bsum);
    k_scanb<<<1, 64, 0, stream>>>(bsum, bofs, NB_SCAN);
    k_rowstart<<<NB_SCAN, 256, 0, stream>>>(degcnt, bofs, row_start);
    k_fill<<<(N_EDGES + BS - 1) / BS, BS, 0, stream>>>(src, dst, row_start, degcnt, csr);

    // graph_t pooling + counts
    k_graphstat<<<(N_NODES + 63) / 64, 128, 0, stream>>>(x, batch, gt_sum);
    k_gcnt<<<(N_GRAPHS + 63) / 64, 64, 0, stream>>>(batch, gcnt);

    // conv1: z1 = A_hat * X[:, :64]  (gather on raw 64-dim features)
    k_gather1<<<N_NODES / 4, 256, 0, stream>>>(csr, row_start, dinv, x, A);
    // h1 = relu(z1 @ W1 + b1)
    k_gemm<64, true><<<(N_NODES + 7) / 8, 128, 0, stream>>>(A, W1, b1, B, N_NODES);

    // conv2 pooled: gsum2[g] = sum_{node in g} (A_hat h1)[node]
    k_gather2<<<N_NODES / 4, 256, 0, stream>>>(csr, row_start, dinv, B, batch, gsum2);

    // final: z = (gsum2/cnt) @ W2 + b2 ; MLP
    k_mlp<<<N_GRAPHS, 128, 0, stream>>>(gsum2, gt_sum, gcnt, W2, b2, Wm1, bm1, Wm2, bm2, out);
}

// Round 4
// 328.806 us; speedup vs baseline: 5.4539x; 1.4693x over previous
//
#include <hip/hip_runtime.h>
#include <hip/hip_bf16.h>

#define N_NODES 100000
#define N_EDGES 1600000
#define N_GRAPHS 512
#define NODE_DIM 64
#define GRAPH_DIM 16
#define HIDDEN 128
#define OUT_DIM 8

#define NBUCKETS 391      // ceil(N_NODES/256)
#define BIN_CAP 8192      // per-bucket bin capacity (avg load 4092, +64 sigma)
#define EPB 4096          // edges per binning block

// ---------------- phase A: bin edges by dst>>8 with block-aggregated cursors ----------------

__global__ void k_binplace(const int* __restrict__ src, const int* __restrict__ dst,
                           int* __restrict__ gcur, int2* __restrict__ bin) {
    __shared__ int cnt[NBUCKETS];
    __shared__ int base[NBUCKETS];
    int t = threadIdx.x;
    for (int i = t; i < NBUCKETS; i += 256) cnt[i] = 0;
    __syncthreads();
    int e0 = blockIdx.x * EPB;
#pragma unroll
    for (int k = 0; k < EPB / 256; k++) {
        int e = e0 + k * 256 + t;
        if (e < N_EDGES) atomicAdd(&cnt[dst[e] >> 8], 1);
    }
    __syncthreads();
    for (int i = t; i < NBUCKETS; i += 256) {
        int c = cnt[i];
        base[i] = (c > 0) ? atomicAdd(&gcur[i], c) : 0;
        cnt[i] = 0;
    }
    __syncthreads();
#pragma unroll
    for (int k = 0; k < EPB / 256; k++) {
        int e = e0 + k * 256 + t;
        if (e < N_EDGES) {
            int d = dst[e];
            int b = d >> 8;
            int p = atomicAdd(&cnt[b], 1);
            bin[(size_t)b * BIN_CAP + base[b] + p] = make_int2(src[e], d);
        }
    }
}

// ---------------- phase B1: per-bucket degree count (coalesced degcnt write) ----------------

__global__ void k_degB(const int* __restrict__ gcur, const int2* __restrict__ bin,
                       int* __restrict__ degcnt) {
    __shared__ int cnt[256];
    int b = blockIdx.x;
    cnt[threadIdx.x] = 0;
    __syncthreads();
    int n = gcur[b];
    const int2* seg = bin + (size_t)b * BIN_CAP;
    for (int i = threadIdx.x; i < n; i += 256) atomicAdd(&cnt[seg[i].y & 255], 1);
    __syncthreads();
    degcnt[b * 256 + threadIdx.x] = cnt[threadIdx.x];  // tail nodes get 0
}

// ---------------- prefix scan over degcnt -> row_start (exclusive) ----------------

__global__ void k_blocksum(const int* __restrict__ cnt, int* __restrict__ bsum) {
    __shared__ int s[256];
    int i = blockIdx.x * 256 + threadIdx.x;
    s[threadIdx.x] = (i < N_NODES) ? cnt[i] : 0;
    __syncthreads();
    for (int o = 128; o > 0; o >>= 1) {
        if (threadIdx.x < o) s[threadIdx.x] += s[threadIdx.x + o];
        __syncthreads();
    }
    if (threadIdx.x == 0) bsum[blockIdx.x] = s[0];
}

__global__ void k_scanb(const int* __restrict__ bsum, int* __restrict__ bofs, int nb) {
    if (threadIdx.x == 0) {
        int a = 0;
        for (int i = 0; i < nb; i++) { bofs[i] = a; a += bsum[i]; }
    }
}

__global__ void k_rowstart(const int* __restrict__ cnt, const int* __restrict__ bofs,
                           int* __restrict__ row_start) {
    __shared__ int s[256];
    int i = blockIdx.x * 256 + threadIdx.x;
    int v = (i < N_NODES) ? cnt[i] : 0;
    s[threadIdx.x] = v;
    __syncthreads();
    for (int o = 1; o < 256; o <<= 1) {
        int t = (threadIdx.x >= o) ? s[threadIdx.x - o] : 0;
        __syncthreads();
        s[threadIdx.x] += t;
        __syncthreads();
    }
    if (i < N_NODES) row_start[i] = bofs[blockIdx.x] + s[threadIdx.x] - v;  // exclusive
}

__global__ void k_dinv(const int* __restrict__ degcnt, float* __restrict__ dinv) {
    int i = blockIdx.x * blockDim.x + threadIdx.x;
    if (i < N_NODES) dinv[i] = rsqrtf((float)degcnt[i] + 1.0f);
}

// ---------------- phase B2: per-bucket CSR fill via LDS positions ----------------

__global__ void k_fillB(const int* __restrict__ gcur, const int2* __restrict__ bin,
                        const int* __restrict__ row_start, int* __restrict__ csr) {
    __shared__ int cnt[256];
    int b = blockIdx.x;
    cnt[threadIdx.x] = 0;
    __syncthreads();
    int n = gcur[b];
    const int2* seg = bin + (size_t)b * BIN_CAP;
    for (int i = threadIdx.x; i < n; i += 256) {
        int2 e = seg[i];
        int pos = row_start[e.y] + atomicAdd(&cnt[e.y & 255], 1);
        csr[pos] = e.x;
    }
}

// ---------------- pack x[:, :64] to bf16 ----------------

__global__ void k_packx(const float* __restrict__ x, ushort* __restrict__ xb) {
    int i = blockIdx.x * 256 + threadIdx.x;  // over N_NODES*32 float2s
    if (i >= N_NODES * 32) return;
    int node = i >> 5, c2 = i & 31;
    float2 v = *(const float2*)&x[(size_t)node * 80 + c2 * 2];
    __hip_bfloat16 lo = __float2bfloat16(v.x);
    __hip_bfloat16 hi = __float2bfloat16(v.y);
    ushort2 pv = make_ushort2(*(ushort*)&lo, *(ushort*)&hi);
    ((ushort2*)xb)[i] = pv;
}

// ---------------- graph feature pooling (x[:,64:80]) with sorted-batch flush ----------------

__global__ void k_graphstat(const float* __restrict__ x, const int* __restrict__ batch,
                            float* __restrict__ gt_sum) {
    int c = threadIdx.x & 15;
    int sub = threadIdx.x >> 4;  // 0..7
    int i0 = blockIdx.x * 64;
    int iend = min(i0 + 64, N_NODES);
    float acc = 0.0f;
    int g = -1;
    for (int i = i0 + sub; i < iend; i += 8) {
        int bi = batch[i];
        if (bi != g) {
            if (g >= 0) atomicAdd(&gt_sum[g * GRAPH_DIM + c], acc);
            acc = 0.0f; g = bi;
        }
        acc += x[(size_t)i * 80 + NODE_DIM + c];
    }
    if (g >= 0) atomicAdd(&gt_sum[g * GRAPH_DIM + c], acc);
}

// ---------------- per-graph node counts via binary search (batch sorted) ----------------

__global__ void k_gcnt(const int* __restrict__ batch, int* __restrict__ gcnt) {
    int g = blockIdx.x * blockDim.x + threadIdx.x;
    if (g >= N_GRAPHS) return;
    int lo = 0, hi = N_NODES;
    while (lo < hi) { int m = (lo + hi) >> 1; if (batch[m] < g) lo = m + 1; else hi = m; }
    int a = lo;
    lo = 0; hi = N_NODES;
    while (lo < hi) { int m = (lo + hi) >> 1; if (batch[m] < g + 1) lo = m + 1; else hi = m; }
    gcnt[g] = lo - a;
}

// ---------------- gather1: z = A_hat * x64 (bf16 operand, f32 accum) ----------------

__global__ void k_gather1(const int* __restrict__ csr, const int* __restrict__ row_start,
                          const float* __restrict__ dinv, const ushort* __restrict__ xb,
                          float* __restrict__ z) {
    int node = blockIdx.x * 4 + (threadIdx.x >> 6);
    int lane = threadIdx.x & 63;
    int rs = row_start[node];
    int re = (node == N_NODES - 1) ? N_EDGES : row_start[node + 1];
    float di = dinv[node];
    float a0 = 0.f, a1 = 0.f, a2 = 0.f, a3 = 0.f;
    int k = rs;
    for (; k + 4 <= re; k += 4) {
        int s0 = csr[k], s1 = csr[k + 1], s2 = csr[k + 2], s3 = csr[k + 3];
        float w0 = dinv[s0] * di, w1 = dinv[s1] * di, w2 = dinv[s2] * di, w3 = dinv[s3] * di;
        a0 += w0 * __uint_as_float((unsigned)xb[(size_t)s0 * 64 + lane] << 16);
        a1 += w1 * __uint_as_float((unsigned)xb[(size_t)s1 * 64 + lane] << 16);
        a2 += w2 * __uint_as_float((unsigned)xb[(size_t)s2 * 64 + lane] << 16);
        a3 += w3 * __uint_as_float((unsigned)xb[(size_t)s3 * 64 + lane] << 16);
    }
    for (; k < re; k++) {
        int s0 = csr[k];
        a0 += dinv[s0] * di * __uint_as_float((unsigned)xb[(size_t)s0 * 64 + lane] << 16);
    }
    float self = __uint_as_float((unsigned)xb[(size_t)node * 64 + lane] << 16);
    z[(size_t)node * 64 + lane] = a0 + a1 + a2 + a3 + di * di * self;
}

// ---------------- GEMM: h1(bf16)[nrows x 128] = relu(z[nrows x 64] * W1 + b1) ----------------

__global__ void k_gemm64(const float* __restrict__ A, const float* __restrict__ W,
                         const float* __restrict__ bias, ushort* __restrict__ C, int nrows) {
    const int TM = 8, K = 64;
    __shared__ float As[TM][K];
    int row0 = blockIdx.x * TM;
    int j = threadIdx.x;  // 0..127
    for (int idx = threadIdx.x; idx < TM * K; idx += 128) {
        int m = idx / K, k = idx % K;
        int r = row0 + m;
        As[m][k] = (r < nrows) ? A[(size_t)r * K + k] : 0.0f;
    }
    __syncthreads();
    float acc[TM];
#pragma unroll
    for (int m = 0; m < TM; m++) acc[m] = 0.0f;
    for (int k = 0; k < K; k++) {
        float w = W[k * 128 + j];
#pragma unroll
        for (int m = 0; m < TM; m++) acc[m] += As[m][k] * w;
    }
    float b = bias[j];
#pragma unroll
    for (int m = 0; m < TM; m++) {
        int r = row0 + m;
        if (r < nrows) {
            float v = fmaxf(acc[m] + b, 0.0f);
            __hip_bfloat16 h = __float2bfloat16(v);
            C[(size_t)r * 128 + j] = *(ushort*)&h;
        }
    }
}

// ---------------- gather2 (bf16 h1) + fused mean-pool numerator ----------------

__global__ void k_gather2(const int* __restrict__ csr, const int* __restrict__ row_start,
                          const float* __restrict__ dinv, const unsigned* __restrict__ h,
                          const int* __restrict__ batch, float* __restrict__ gsum2) {
    __shared__ float2 red[4][64];
    int w = threadIdx.x >> 6;
    int node = blockIdx.x * 4 + w;
    int lane = threadIdx.x & 63;
    int rs = row_start[node];
    int re = (node == N_NODES - 1) ? N_EDGES : row_start[node + 1];
    float di = dinv[node];
    float ax0 = 0.f, ay0 = 0.f, ax1 = 0.f, ay1 = 0.f;
    float ax2 = 0.f, ay2 = 0.f, ax3 = 0.f, ay3 = 0.f;
    int k = rs;
    for (; k + 4 <= re; k += 4) {
        int s0 = csr[k], s1 = csr[k + 1], s2 = csr[k + 2], s3 = csr[k + 3];
        float w0 = dinv[s0] * di, w1 = dinv[s1] * di, w2 = dinv[s2] * di, w3 = dinv[s3] * di;
        unsigned u0 = h[(size_t)s0 * 64 + lane];
        unsigned u1 = h[(size_t)s1 * 64 + lane];
        unsigned u2 = h[(size_t)s2 * 64 + lane];
        unsigned u3 = h[(size_t)s3 * 64 + lane];
        ax0 += w0 * __uint_as_float(u0 << 16); ay0 += w0 * __uint_as_float(u0 & 0xffff0000u);
        ax1 += w1 * __uint_as_float(u1 << 16); ay1 += w1 * __uint_as_float(u1 & 0xffff0000u);
        ax2 += w2 * __uint_as_float(u2 << 16); ay2 += w2 * __uint_as_float(u2 & 0xffff0000u);
        ax3 += w3 * __uint_as_float(u3 << 16); ay3 += w3 * __uint_as_float(u3 & 0xffff0000u);
    }
    for (; k < re; k++) {
        int s0 = csr[k];
        float w0 = dinv[s0] * di;
        unsigned u0 = h[(size_t)s0 * 64 + lane];
        ax0 += w0 * __uint_as_float(u0 << 16); ay0 += w0 * __uint_as_float(u0 & 0xffff0000u);
    }
    unsigned us = h[(size_t)node * 64 + lane];
    float dd = di * di;
    float2 r;
    r.x = ax0 + ax1 + ax2 + ax3 + dd * __uint_as_float(us << 16);
    r.y = ay0 + ay1 + ay2 + ay3 + dd * __uint_as_float(us & 0xffff0000u);
    red[w][lane] = r;
    __syncthreads();
    int g0 = batch[blockIdx.x * 4];
    int g3 = batch[blockIdx.x * 4 + 3];
    if (g0 == g3) {
        if (w == 0) {
            float sx = red[0][lane].x + red[1][lane].x + red[2][lane].x + red[3][lane].x;
            float sy = red[0][lane].y + red[1][lane].y + red[2][lane].y + red[3][lane].y;
            atomicAdd(&gsum2[g0 * 128 + 2 * lane], sx);
            atomicAdd(&gsum2[g0 * 128 + 2 * lane + 1], sy);
        }
    } else {
        int g = batch[node];
        atomicAdd(&gsum2[g * 128 + 2 * lane], r.x);
        atomicAdd(&gsum2[g * 128 + 2 * lane + 1], r.y);
    }
}

// ---------------- final: z = mean2 @ W2 + b2 ; g=[z, gt_mean]; MLP ----------------

__global__ void k_mlp(const float* __restrict__ gsum2, const float* __restrict__ gt_sum,
                      const int* __restrict__ gcnt, const float* __restrict__ W2,
                      const float* __restrict__ b2, const float* __restrict__ Wm1,
                      const float* __restrict__ bm1, const float* __restrict__ Wm2,
                      const float* __restrict__ bm2, float* __restrict__ out) {
    __shared__ float srow[HIDDEN];
    __shared__ float g144[HIDDEN + GRAPH_DIM];
    __shared__ float sm[HIDDEN];
    int b = blockIdx.x;
    int j = threadIdx.x;  // 0..127
    float inv = 1.0f / fmaxf((float)gcnt[b], 1.0f);
    srow[j] = gsum2[b * 128 + j] * inv;
    if (j < GRAPH_DIM) g144[128 + j] = gt_sum[b * GRAPH_DIM + j] * inv;
    __syncthreads();
    float z = b2[j];
    for (int k = 0; k < 128; k++) z += srow[k] * W2[k * 128 + j];
    g144[j] = z;
    __syncthreads();
    float acc = bm1[j];
    for (int k = 0; k < HIDDEN + GRAPH_DIM; k++) acc += g144[k] * Wm1[k * 128 + j];
    sm[j] = fmaxf(acc, 0.0f);
    __syncthreads();
    if (j < OUT_DIM) {
        float o = bm2[j];
        for (int k = 0; k < 128; k++) o += sm[k] * Wm2[k * OUT_DIM + j];
        out[b * OUT_DIM + j] = o;
    }
}

extern "C" void kernel_launch(void* const* d_in, const int* in_sizes, int n_in,
                              void* d_out, int out_size, void* d_ws, size_t ws_size,
                              hipStream_t stream) {
    const float* x    = (const float*)d_in[0];
    const int*   edge = (const int*)d_in[1];
    const int*   src  = edge;
    const int*   dst  = edge + N_EDGES;
    const int*   batch= (const int*)d_in[2];
    const float* W1   = (const float*)d_in[3];
    const float* b1   = (const float*)d_in[4];
    const float* W2   = (const float*)d_in[5];
    const float* b2   = (const float*)d_in[6];
    const float* Wm1  = (const float*)d_in[7];
    const float* bm1  = (const float*)d_in[8];
    const float* Wm2  = (const float*)d_in[9];
    const float* bm2  = (const float*)d_in[10];
    float* out = (float*)d_out;

    // workspace layout (~98 MB); keep 8B-aligned chunks first
    char* ws = (char*)d_ws;
    char* p = ws;
    int2*  bin      = (int2*)p;      p += (size_t)NBUCKETS * BIN_CAP * 8;   // 25.6 MB
    float* A        = (float*)p;     p += (size_t)N_NODES * 64 * 4;         // z1 25.6 MB
    ushort* h1b     = (ushort*)p;    p += (size_t)N_NODES * 128 * 2;        // h1 bf16 25.6 MB
    ushort* xb      = (ushort*)p;    p += (size_t)N_NODES * 64 * 2;         // x bf16 12.8 MB
    int*   csr      = (int*)p;       p += (size_t)N_EDGES * 4;              // 6.4 MB
    int*   degcnt   = (int*)p;       p += (size_t)NBUCKETS * 256 * 4;       // 100096 ints
    int*   row_start= (int*)p;       p += (size_t)N_NODES * 4;
    float* dinv     = (float*)p;     p += (size_t)N_NODES * 4;
    int*   gcur     = (int*)p;       p += (size_t)NBUCKETS * 4;
    int*   bsum     = (int*)p;       p += 512 * 4;
    int*   bofs     = (int*)p;       p += 512 * 4;
    float* gt_sum   = (float*)p;     p += (size_t)N_GRAPHS * GRAPH_DIM * 4;
    int*   gcnt     = (int*)p;       p += (size_t)N_GRAPHS * 4;
    float* gsum2    = (float*)p;     p += (size_t)N_GRAPHS * 128 * 4;

    hipMemsetAsync(gcur,   0, (size_t)NBUCKETS * 4, stream);
    hipMemsetAsync(gt_sum, 0, (size_t)N_GRAPHS * GRAPH_DIM * 4, stream);
    hipMemsetAsync(gsum2,  0, (size_t)N_GRAPHS * 128 * 4, stream);

    // CSR build: bin -> degrees -> scan -> fill
    k_binplace<<<(N_EDGES + EPB - 1) / EPB, 256, 0, stream>>>(src, dst, gcur, bin);
    k_degB<<<NBUCKETS, 256, 0, stream>>>(gcur, bin, degcnt);
    k_blocksum<<<NBUCKETS, 256, 0, stream>>>(degcnt, bsum);
    k_scanb<<<1, 64, 0, stream>>>(bsum, bofs, NBUCKETS);
    k_rowstart<<<NBUCKETS, 256, 0, stream>>>(degcnt, bofs, row_start);
    k_dinv<<<NBUCKETS, 256, 0, stream>>>(degcnt, dinv);
    k_fillB<<<NBUCKETS, 256, 0, stream>>>(gcur, bin, row_start, csr);

    // bf16 pack of x node features
    k_packx<<<(N_NODES * 32 + 255) / 256, 256, 0, stream>>>(x, xb);

    // graph_t pooling + counts
    k_graphstat<<<(N_NODES + 63) / 64, 128, 0, stream>>>(x, batch, gt_sum);
    k_gcnt<<<(N_GRAPHS + 63) / 64, 64, 0, stream>>>(batch, gcnt);

    // conv1: z1 = A_hat * x64 ; h1 = relu(z1 @ W1 + b1) (bf16)
    k_gather1<<<N_NODES / 4, 256, 0, stream>>>(csr, row_start, dinv, xb, A);
    k_gemm64<<<(N_NODES + 7) / 8, 128, 0, stream>>>(A, W1, b1, h1b, N_NODES);

    // conv2 pooled: gsum2[g] = sum_{node in g} (A_hat h1)[node]
    k_gather2<<<N_NODES / 4, 256, 0, stream>>>(csr, row_start, dinv, (const unsigned*)h1b, batch, gsum2);

    // final: z = (gsum2/cnt) @ W2 + b2 ; MLP
    k_mlp<<<N_GRAPHS, 128, 0, stream>>>(gsum2, gt_sum, gcnt, W2, b2, Wm1, bm1, Wm2, bm2, out);
}

// Round 5
// 267.884 us; speedup vs baseline: 6.6942x; 1.2274x over previous
//
#include <hip/hip_runtime.h>
#include <hip/hip_bf16.h>

#define N_NODES 100000
#define N_EDGES 1600000
#define N_GRAPHS 512
#define NODE_DIM 64
#define GRAPH_DIM 16
#define HIDDEN 128
#define OUT_DIM 8

#define NBUCKETS 391      // ceil(N_NODES/256)
#define BIN_CAP 8192      // per-bucket bin capacity (avg 4092)
#define EPB 4096          // edges per binning block

// ---------------- phase A: bin edges by dst>>8; entry = (src<<8)|(dst&255) ----------------

__global__ __launch_bounds__(256) void k_binplace(const int* __restrict__ src,
                                                  const int* __restrict__ dst,
                                                  int* __restrict__ gcur,
                                                  unsigned* __restrict__ bin) {
    __shared__ int cnt[NBUCKETS];
    __shared__ int base[NBUCKETS];
    int t = threadIdx.x;
    for (int i = t; i < NBUCKETS; i += 256) cnt[i] = 0;
    __syncthreads();
    int e0 = blockIdx.x * EPB;
#pragma unroll
    for (int k = 0; k < EPB / 256; k++) {
        int e = e0 + k * 256 + t;
        if (e < N_EDGES) atomicAdd(&cnt[dst[e] >> 8], 1);
    }
    __syncthreads();
    for (int i = t; i < NBUCKETS; i += 256) {
        int c = cnt[i];
        base[i] = (c > 0) ? atomicAdd(&gcur[i], c) : 0;
        cnt[i] = 0;
    }
    __syncthreads();
#pragma unroll
    for (int k = 0; k < EPB / 256; k++) {
        int e = e0 + k * 256 + t;
        if (e < N_EDGES) {
            int d = dst[e];
            int b = d >> 8;
            int p = atomicAdd(&cnt[b], 1);
            bin[(size_t)b * BIN_CAP + base[b] + p] = ((unsigned)src[e] << 8) | (unsigned)(d & 255);
        }
    }
}

// ---------------- phase B1: per-bucket degree count + dinv + block sum ----------------

__global__ __launch_bounds__(256) void k_degBf(const int* __restrict__ gcur,
                                               const unsigned* __restrict__ bin,
                                               int* __restrict__ degcnt,
                                               float* __restrict__ dinv,
                                               int* __restrict__ bsum) {
    __shared__ int cnt[256];
    int b = blockIdx.x, t = threadIdx.x;
    cnt[t] = 0;
    __syncthreads();
    int n = gcur[b];
    const unsigned* seg = bin + (size_t)b * BIN_CAP;
    for (int i = t; i < n; i += 256) atomicAdd(&cnt[seg[i] & 255u], 1);
    __syncthreads();
    int c = cnt[t];
    int node = b * 256 + t;
    if (node < N_NODES) {
        degcnt[node] = c;
        dinv[node] = rsqrtf((float)c + 1.0f);
    }
    __syncthreads();
    for (int o = 128; o > 0; o >>= 1) {
        if (t < o) cnt[t] += cnt[t + o];
        __syncthreads();
    }
    if (t == 0) bsum[b] = cnt[0];
}

// ---------------- exclusive scan of bsum -> bofs (one 512-thread block) ----------------

__global__ __launch_bounds__(512) void k_scanb(const int* __restrict__ bsum,
                                               int* __restrict__ bofs) {
    __shared__ int s[512];
    int t = threadIdx.x;
    int v = (t < NBUCKETS) ? bsum[t] : 0;
    s[t] = v;
    __syncthreads();
    for (int o = 1; o < 512; o <<= 1) {
        int u = (t >= o) ? s[t - o] : 0;
        __syncthreads();
        s[t] += u;
        __syncthreads();
    }
    if (t < NBUCKETS) bofs[t] = s[t] - v;
}

// ---------------- phase B2: fused rowstart + CSR fill (src + f32 weight) ----------------

__global__ __launch_bounds__(256) void k_rowfill(const int* __restrict__ degcnt,
                                                 const int* __restrict__ bofs,
                                                 const int* __restrict__ gcur,
                                                 const unsigned* __restrict__ bin,
                                                 const float* __restrict__ dinv,
                                                 int* __restrict__ row_start,
                                                 int* __restrict__ csr,
                                                 float* __restrict__ csrw) {
    __shared__ int sc[256];
    __shared__ int rsl[256];
    __shared__ int cnt[256];
    __shared__ float dl[256];
    int b = blockIdx.x, t = threadIdx.x;
    int node = b * 256 + t;
    int v = (node < N_NODES) ? degcnt[node] : 0;
    sc[t] = v;
    __syncthreads();
    for (int o = 1; o < 256; o <<= 1) {
        int u = (t >= o) ? sc[t - o] : 0;
        __syncthreads();
        sc[t] += u;
        __syncthreads();
    }
    int rs = bofs[b] + sc[t] - v;  // exclusive
    if (node < N_NODES) row_start[node] = rs;
    rsl[t] = rs;
    cnt[t] = 0;
    dl[t] = rsqrtf((float)v + 1.0f);
    __syncthreads();
    int n = gcur[b];
    const unsigned* seg = bin + (size_t)b * BIN_CAP;
    for (int i = t; i < n; i += 256) {
        unsigned e = seg[i];
        int dlidx = (int)(e & 255u);
        int s = (int)(e >> 8);
        int pos = rsl[dlidx] + atomicAdd(&cnt[dlidx], 1);
        csr[pos] = s;
        csrw[pos] = dinv[s] * dl[dlidx];
    }
}

// ---------------- fused: pack x[:, :64] to bf16 + graph feature pooling ----------------

__global__ __launch_bounds__(256) void k_packstat(const float* __restrict__ x,
                                                  const int* __restrict__ batch,
                                                  ushort* __restrict__ xb,
                                                  float* __restrict__ gt_sum) {
    int t = threadIdx.x;
    int i0 = blockIdx.x * 64;
    // pack 64 nodes x 32 float2
    for (int idx = t; idx < 64 * 32; idx += 256) {
        int node = i0 + (idx >> 5);
        if (node < N_NODES) {
            int c2 = idx & 31;
            float2 v = *(const float2*)&x[(size_t)node * 80 + c2 * 2];
            __hip_bfloat16 lo = __float2bfloat16(v.x);
            __hip_bfloat16 hi = __float2bfloat16(v.y);
            ushort2 pv = make_ushort2(*(ushort*)&lo, *(ushort*)&hi);
            ((ushort2*)xb)[(size_t)node * 32 + c2] = pv;
        }
    }
    // graph stats over x[:,64:80], sorted-batch flush
    int c = t & 15, sub = t >> 4;  // 16 subs x 16 channels
    int iend = min(i0 + 64, N_NODES);
    float acc = 0.0f;
    int g = -1;
    for (int i = i0 + sub; i < iend; i += 16) {
        int bi = batch[i];
        if (bi != g) {
            if (g >= 0) atomicAdd(&gt_sum[g * GRAPH_DIM + c], acc);
            acc = 0.0f; g = bi;
        }
        acc += x[(size_t)i * 80 + NODE_DIM + c];
    }
    if (g >= 0) atomicAdd(&gt_sum[g * GRAPH_DIM + c], acc);
}

// ---------------- gather1: z = A_hat * x64 (bf16 rows, f32 weights), 2 nodes/wave ----------------

#define LDX(s_) __uint_as_float((unsigned)xb[(size_t)(s_)*64 + lane] << 16)

__global__ __launch_bounds__(256) void k_gather1(const int* __restrict__ csr,
                                                 const float* __restrict__ csrw,
                                                 const int* __restrict__ row_start,
                                                 const float* __restrict__ dinv,
                                                 const ushort* __restrict__ xb,
                                                 float* __restrict__ z) {
    int w = threadIdx.x >> 6, lane = threadIdx.x & 63;
    int nA = blockIdx.x * 8 + w * 2;
    int nB = nA + 1;
    int rsA = row_start[nA], reA = (nA == N_NODES - 1) ? N_EDGES : row_start[nA + 1];
    int rsB = row_start[nB], reB = (nB == N_NODES - 1) ? N_EDGES : row_start[nB + 1];
    float aA0 = 0.f, aA1 = 0.f, aA2 = 0.f, aA3 = 0.f;
    float aB0 = 0.f, aB1 = 0.f, aB2 = 0.f, aB3 = 0.f;
    int kA = rsA, kB = rsB;
    while (kA + 4 <= reA && kB + 4 <= reB) {
        int a0 = csr[kA], a1 = csr[kA + 1], a2 = csr[kA + 2], a3 = csr[kA + 3];
        int b0 = csr[kB], b1 = csr[kB + 1], b2 = csr[kB + 2], b3 = csr[kB + 3];
        float wa0 = csrw[kA], wa1 = csrw[kA + 1], wa2 = csrw[kA + 2], wa3 = csrw[kA + 3];
        float wb0 = csrw[kB], wb1 = csrw[kB + 1], wb2 = csrw[kB + 2], wb3 = csrw[kB + 3];
        float vA0 = LDX(a0), vA1 = LDX(a1), vA2 = LDX(a2), vA3 = LDX(a3);
        float vB0 = LDX(b0), vB1 = LDX(b1), vB2 = LDX(b2), vB3 = LDX(b3);
        aA0 += wa0 * vA0; aA1 += wa1 * vA1; aA2 += wa2 * vA2; aA3 += wa3 * vA3;
        aB0 += wb0 * vB0; aB1 += wb1 * vB1; aB2 += wb2 * vB2; aB3 += wb3 * vB3;
        kA += 4; kB += 4;
    }
    while (kA + 4 <= reA) {
        int a0 = csr[kA], a1 = csr[kA + 1], a2 = csr[kA + 2], a3 = csr[kA + 3];
        float wa0 = csrw[kA], wa1 = csrw[kA + 1], wa2 = csrw[kA + 2], wa3 = csrw[kA + 3];
        float vA0 = LDX(a0), vA1 = LDX(a1), vA2 = LDX(a2), vA3 = LDX(a3);
        aA0 += wa0 * vA0; aA1 += wa1 * vA1; aA2 += wa2 * vA2; aA3 += wa3 * vA3;
        kA += 4;
    }
    while (kB + 4 <= reB) {
        int b0 = csr[kB], b1 = csr[kB + 1], b2 = csr[kB + 2], b3 = csr[kB + 3];
        float wb0 = csrw[kB], wb1 = csrw[kB + 1], wb2 = csrw[kB + 2], wb3 = csrw[kB + 3];
        float vB0 = LDX(b0), vB1 = LDX(b1), vB2 = LDX(b2), vB3 = LDX(b3);
        aB0 += wb0 * vB0; aB1 += wb1 * vB1; aB2 += wb2 * vB2; aB3 += wb3 * vB3;
        kB += 4;
    }
    while (kA < reA && kB < reB) {
        int a0 = csr[kA]; int b0 = csr[kB];
        float wa0 = csrw[kA], wb0 = csrw[kB];
        aA0 += wa0 * LDX(a0); aB0 += wb0 * LDX(b0);
        kA++; kB++;
    }
    while (kA < reA) { int a0 = csr[kA]; aA0 += csrw[kA] * LDX(a0); kA++; }
    while (kB < reB) { int b0 = csr[kB]; aB0 += csrw[kB] * LDX(b0); kB++; }
    float dA = dinv[nA], dB = dinv[nB];
    z[(size_t)nA * 64 + lane] = aA0 + aA1 + aA2 + aA3 + dA * dA * LDX(nA);
    z[(size_t)nB * 64 + lane] = aB0 + aB1 + aB2 + aB3 + dB * dB * LDX(nB);
}

// ---------------- GEMM: h1(bf16) = relu(z @ W1 + b1) ----------------

__global__ __launch_bounds__(128) void k_gemm64(const float* __restrict__ A,
                                                const float* __restrict__ W,
                                                const float* __restrict__ bias,
                                                ushort* __restrict__ C, int nrows) {
    const int TM = 8, K = 64;
    __shared__ float As[TM][K];
    int row0 = blockIdx.x * TM;
    int j = threadIdx.x;  // 0..127
    for (int idx = threadIdx.x; idx < TM * K; idx += 128) {
        int m = idx / K, k = idx % K;
        int r = row0 + m;
        As[m][k] = (r < nrows) ? A[(size_t)r * K + k] : 0.0f;
    }
    __syncthreads();
    float acc[TM];
#pragma unroll
    for (int m = 0; m < TM; m++) acc[m] = 0.0f;
    for (int k = 0; k < K; k++) {
        float w = W[k * 128 + j];
#pragma unroll
        for (int m = 0; m < TM; m++) acc[m] += As[m][k] * w;
    }
    float b = bias[j];
#pragma unroll
    for (int m = 0; m < TM; m++) {
        int r = row0 + m;
        if (r < nrows) {
            float v = fmaxf(acc[m] + b, 0.0f);
            __hip_bfloat16 hv = __float2bfloat16(v);
            C[(size_t)r * 128 + j] = *(ushort*)&hv;
        }
    }
}

// ---------------- gather2 (bf16x2 rows, f32 weights) + fused mean-pool, 2 nodes/wave ----------------

__global__ __launch_bounds__(256) void k_gather2(const int* __restrict__ csr,
                                                 const float* __restrict__ csrw,
                                                 const int* __restrict__ row_start,
                                                 const float* __restrict__ dinv,
                                                 const unsigned* __restrict__ h,
                                                 const int* __restrict__ batch,
                                                 float* __restrict__ gsum2) {
    __shared__ float2 red[8][64];
    int w = threadIdx.x >> 6, lane = threadIdx.x & 63;
    int nA = blockIdx.x * 8 + w * 2;
    int nB = nA + 1;
    int rsA = row_start[nA], reA = (nA == N_NODES - 1) ? N_EDGES : row_start[nA + 1];
    int rsB = row_start[nB], reB = (nB == N_NODES - 1) ? N_EDGES : row_start[nB + 1];
    float2 aA0 = {0.f,0.f}, aA1 = {0.f,0.f}, aA2 = {0.f,0.f}, aA3 = {0.f,0.f};
    float2 aB0 = {0.f,0.f}, aB1 = {0.f,0.f}, aB2 = {0.f,0.f}, aB3 = {0.f,0.f};
    int kA = rsA, kB = rsB;
#define FMA2(acc_, w_, u_) { acc_.x += (w_) * __uint_as_float((u_) << 16); \
                             acc_.y += (w_) * __uint_as_float((u_) & 0xffff0000u); }
    while (kA + 4 <= reA && kB + 4 <= reB) {
        int a0 = csr[kA], a1 = csr[kA + 1], a2 = csr[kA + 2], a3 = csr[kA + 3];
        int b0 = csr[kB], b1 = csr[kB + 1], b2 = csr[kB + 2], b3 = csr[kB + 3];
        float wa0 = csrw[kA], wa1 = csrw[kA + 1], wa2 = csrw[kA + 2], wa3 = csrw[kA + 3];
        float wb0 = csrw[kB], wb1 = csrw[kB + 1], wb2 = csrw[kB + 2], wb3 = csrw[kB + 3];
        unsigned uA0 = h[(size_t)a0 * 64 + lane], uA1 = h[(size_t)a1 * 64 + lane];
        unsigned uA2 = h[(size_t)a2 * 64 + lane], uA3 = h[(size_t)a3 * 64 + lane];
        unsigned uB0 = h[(size_t)b0 * 64 + lane], uB1 = h[(size_t)b1 * 64 + lane];
        unsigned uB2 = h[(size_t)b2 * 64 + lane], uB3 = h[(size_t)b3 * 64 + lane];
        FMA2(aA0, wa0, uA0); FMA2(aA1, wa1, uA1); FMA2(aA2, wa2, uA2); FMA2(aA3, wa3, uA3);
        FMA2(aB0, wb0, uB0); FMA2(aB1, wb1, uB1); FMA2(aB2, wb2, uB2); FMA2(aB3, wb3, uB3);
        kA += 4; kB += 4;
    }
    while (kA + 4 <= reA) {
        int a0 = csr[kA], a1 = csr[kA + 1], a2 = csr[kA + 2], a3 = csr[kA + 3];
        float wa0 = csrw[kA], wa1 = csrw[kA + 1], wa2 = csrw[kA + 2], wa3 = csrw[kA + 3];
        unsigned uA0 = h[(size_t)a0 * 64 + lane], uA1 = h[(size_t)a1 * 64 + lane];
        unsigned uA2 = h[(size_t)a2 * 64 + lane], uA3 = h[(size_t)a3 * 64 + lane];
        FMA2(aA0, wa0, uA0); FMA2(aA1, wa1, uA1); FMA2(aA2, wa2, uA2); FMA2(aA3, wa3, uA3);
        kA += 4;
    }
    while (kB + 4 <= reB) {
        int b0 = csr[kB], b1 = csr[kB + 1], b2 = csr[kB + 2], b3 = csr[kB + 3];
        float wb0 = csrw[kB], wb1 = csrw[kB + 1], wb2 = csrw[kB + 2], wb3 = csrw[kB + 3];
        unsigned uB0 = h[(size_t)b0 * 64 + lane], uB1 = h[(size_t)b1 * 64 + lane];
        unsigned uB2 = h[(size_t)b2 * 64 + lane], uB3 = h[(size_t)b3 * 64 + lane];
        FMA2(aB0, wb0, uB0); FMA2(aB1, wb1, uB1); FMA2(aB2, wb2, uB2); FMA2(aB3, wb3, uB3);
        kB += 4;
    }
    while (kA < reA && kB < reB) {
        int a0 = csr[kA]; int b0 = csr[kB];
        float wa0 = csrw[kA], wb0 = csrw[kB];
        unsigned uA0 = h[(size_t)a0 * 64 + lane], uB0 = h[(size_t)b0 * 64 + lane];
        FMA2(aA0, wa0, uA0); FMA2(aB0, wb0, uB0);
        kA++; kB++;
    }
    while (kA < reA) {
        int a0 = csr[kA]; float wa0 = csrw[kA];
        unsigned uA0 = h[(size_t)a0 * 64 + lane];
        FMA2(aA0, wa0, uA0); kA++;
    }
    while (kB < reB) {
        int b0 = csr[kB]; float wb0 = csrw[kB];
        unsigned uB0 = h[(size_t)b0 * 64 + lane];
        FMA2(aB0, wb0, uB0); kB++;
    }
    float dA = dinv[nA], dB = dinv[nB];
    unsigned usA = h[(size_t)nA * 64 + lane];
    unsigned usB = h[(size_t)nB * 64 + lane];
    float2 rA, rB;
    rA.x = aA0.x + aA1.x + aA2.x + aA3.x + dA * dA * __uint_as_float(usA << 16);
    rA.y = aA0.y + aA1.y + aA2.y + aA3.y + dA * dA * __uint_as_float(usA & 0xffff0000u);
    rB.x = aB0.x + aB1.x + aB2.x + aB3.x + dB * dB * __uint_as_float(usB << 16);
    rB.y = aB0.y + aB1.y + aB2.y + aB3.y + dB * dB * __uint_as_float(usB & 0xffff0000u);
    red[w * 2][lane] = rA;
    red[w * 2 + 1][lane] = rB;
    __syncthreads();
    int g0 = batch[blockIdx.x * 8];
    int g7 = batch[blockIdx.x * 8 + 7];
    if (g0 == g7) {
        if (w == 0) {
            float sx = 0.f, sy = 0.f;
#pragma unroll
            for (int q = 0; q < 8; q++) { sx += red[q][lane].x; sy += red[q][lane].y; }
            atomicAdd(&gsum2[g0 * 128 + 2 * lane], sx);
            atomicAdd(&gsum2[g0 * 128 + 2 * lane + 1], sy);
        }
    } else {
        int gA = batch[nA], gB = batch[nB];
        atomicAdd(&gsum2[gA * 128 + 2 * lane], rA.x);
        atomicAdd(&gsum2[gA * 128 + 2 * lane + 1], rA.y);
        atomicAdd(&gsum2[gB * 128 + 2 * lane], rB.x);
        atomicAdd(&gsum2[gB * 128 + 2 * lane + 1], rB.y);
    }
#undef FMA2
}

// ---------------- final: gcnt (binary search) + z = mean2 @ W2 + b2 ; MLP ----------------

__global__ __launch_bounds__(128) void k_mlp(const float* __restrict__ gsum2,
                                             const float* __restrict__ gt_sum,
                                             const int* __restrict__ batch,
                                             const float* __restrict__ W2,
                                             const float* __restrict__ b2,
                                             const float* __restrict__ Wm1,
                                             const float* __restrict__ bm1,
                                             const float* __restrict__ Wm2,
                                             const float* __restrict__ bm2,
                                             float* __restrict__ out) {
    __shared__ float srow[HIDDEN];
    __shared__ float g144[HIDDEN + GRAPH_DIM];
    __shared__ float sm[HIDDEN];
    __shared__ int cnt_sh;
    int b = blockIdx.x;
    int j = threadIdx.x;  // 0..127
    float raw = gsum2[b * 128 + j];
    float gtraw = (j < GRAPH_DIM) ? gt_sum[b * GRAPH_DIM + j] : 0.0f;
    if (j == 0) {
        int lo = 0, hi = N_NODES;
        while (lo < hi) { int m = (lo + hi) >> 1; if (batch[m] < b) lo = m + 1; else hi = m; }
        int a = lo;
        lo = 0; hi = N_NODES;
        while (lo < hi) { int m = (lo + hi) >> 1; if (batch[m] < b + 1) lo = m + 1; else hi = m; }
        cnt_sh = lo - a;
    }
    __syncthreads();
    float inv = 1.0f / fmaxf((float)cnt_sh, 1.0f);
    srow[j] = raw * inv;
    if (j < GRAPH_DIM) g144[128 + j] = gtraw * inv;
    __syncthreads();
    float z = b2[j];
    for (int k = 0; k < 128; k++) z += srow[k] * W2[k * 128 + j];
    g144[j] = z;
    __syncthreads();
    float acc = bm1[j];
    for (int k = 0; k < HIDDEN + GRAPH_DIM; k++) acc += g144[k] * Wm1[k * 128 + j];
    sm[j] = fmaxf(acc, 0.0f);
    __syncthreads();
    if (j < OUT_DIM) {
        float o = bm2[j];
        for (int k = 0; k < 128; k++) o += sm[k] * Wm2[k * OUT_DIM + j];
        out[b * OUT_DIM + j] = o;
    }
}

extern "C" void kernel_launch(void* const* d_in, const int* in_sizes, int n_in,
                              void* d_out, int out_size, void* d_ws, size_t ws_size,
                              hipStream_t stream) {
    const float* x    = (const float*)d_in[0];
    const int*   edge = (const int*)d_in[1];
    const int*   src  = edge;
    const int*   dst  = edge + N_EDGES;
    const int*   batch= (const int*)d_in[2];
    const float* W1   = (const float*)d_in[3];
    const float* b1   = (const float*)d_in[4];
    const float* W2   = (const float*)d_in[5];
    const float* b2   = (const float*)d_in[6];
    const float* Wm1  = (const float*)d_in[7];
    const float* bm1  = (const float*)d_in[8];
    const float* Wm2  = (const float*)d_in[9];
    const float* bm2  = (const float*)d_in[10];
    float* out = (float*)d_out;

    // workspace layout (~91 MB)
    char* ws = (char*)d_ws;
    char* p = ws;
    unsigned* bin   = (unsigned*)p;  p += (size_t)NBUCKETS * BIN_CAP * 4;   // 12.8 MB
    float* A        = (float*)p;     p += (size_t)N_NODES * 64 * 4;         // z1 25.6 MB
    ushort* h1b     = (ushort*)p;    p += (size_t)N_NODES * 128 * 2;        // h1 bf16 25.6 MB
    ushort* xb      = (ushort*)p;    p += (size_t)N_NODES * 64 * 2;         // x bf16 12.8 MB
    int*   csr      = (int*)p;       p += (size_t)N_EDGES * 4;              // 6.4 MB
    float* csrw     = (float*)p;     p += (size_t)N_EDGES * 4;              // 6.4 MB
    int*   degcnt   = (int*)p;       p += (size_t)NBUCKETS * 256 * 4;
    int*   row_start= (int*)p;       p += (size_t)N_NODES * 4;
    float* dinv     = (float*)p;     p += (size_t)N_NODES * 4;
    int*   gcur     = (int*)p;       p += (size_t)NBUCKETS * 4;
    int*   bsum     = (int*)p;       p += 512 * 4;
    int*   bofs     = (int*)p;       p += 512 * 4;
    float* gt_sum   = (float*)p;     p += (size_t)N_GRAPHS * GRAPH_DIM * 4;
    float* gsum2    = (float*)p;     p += (size_t)N_GRAPHS * 128 * 4;

    hipMemsetAsync(gcur,   0, (size_t)NBUCKETS * 4, stream);
    hipMemsetAsync(gt_sum, 0, (size_t)N_GRAPHS * GRAPH_DIM * 4, stream);
    hipMemsetAsync(gsum2,  0, (size_t)N_GRAPHS * 128 * 4, stream);

    // CSR build
    k_binplace<<<(N_EDGES + EPB - 1) / EPB, 256, 0, stream>>>(src, dst, gcur, bin);
    k_degBf<<<NBUCKETS, 256, 0, stream>>>(gcur, bin, degcnt, dinv, bsum);
    k_scanb<<<1, 512, 0, stream>>>(bsum, bofs);
    k_rowfill<<<NBUCKETS, 256, 0, stream>>>(degcnt, bofs, gcur, bin, dinv, row_start, csr, csrw);

    // bf16 pack + graph stats
    k_packstat<<<(N_NODES + 63) / 64, 256, 0, stream>>>(x, batch, xb, gt_sum);

    // conv1: z1 = A_hat * x64 ; h1 = relu(z1 @ W1 + b1) (bf16)
    k_gather1<<<N_NODES / 8, 256, 0, stream>>>(csr, csrw, row_start, dinv, xb, A);
    k_gemm64<<<(N_NODES + 7) / 8, 128, 0, stream>>>(A, W1, b1, h1b, N_NODES);

    // conv2 pooled: gsum2[g] = sum_{node in g} (A_hat h1)[node]
    k_gather2<<<N_NODES / 8, 256, 0, stream>>>(csr, csrw, row_start, dinv,
                                               (const unsigned*)h1b, batch, gsum2);

    // final: gcnt + z = (gsum2/cnt) @ W2 + b2 ; MLP
    k_mlp<<<N_GRAPHS, 128, 0, stream>>>(gsum2, gt_sum, batch, W2, b2, Wm1, bm1, Wm2, bm2, out);
}

// Round 6
// 258.093 us; speedup vs baseline: 6.9482x; 1.0379x over previous
//
#include <hip/hip_runtime.h>
#include <hip/hip_bf16.h>

#define N_NODES 100000
#define N_EDGES 1600000
#define N_GRAPHS 512
#define NODE_DIM 64
#define GRAPH_DIM 16
#define HIDDEN 128
#define OUT_DIM 8

#define NBUCKETS 391      // ceil(N_NODES/256)
#define BIN_CAP 8192      // per-bucket bin capacity (avg 4092)
#define EPB 4096          // edges per binning block

__device__ __forceinline__ float bflo(unsigned u) { return __uint_as_float(u << 16); }
__device__ __forceinline__ float bfhi(unsigned u) { return __uint_as_float(u & 0xffff0000u); }

// ---------------- phase A: bin edges by dst>>8; entry = (src<<8)|(dst&255) ----------------

__global__ __launch_bounds__(256) void k_binplace(const int* __restrict__ src,
                                                  const int* __restrict__ dst,
                                                  int* __restrict__ gcur,
                                                  unsigned* __restrict__ bin) {
    __shared__ int cnt[NBUCKETS];
    __shared__ int base[NBUCKETS];
    int t = threadIdx.x;
    for (int i = t; i < NBUCKETS; i += 256) cnt[i] = 0;
    __syncthreads();
    int e0 = blockIdx.x * EPB;
#pragma unroll
    for (int k = 0; k < EPB / 256; k++) {
        int e = e0 + k * 256 + t;
        if (e < N_EDGES) atomicAdd(&cnt[dst[e] >> 8], 1);
    }
    __syncthreads();
    for (int i = t; i < NBUCKETS; i += 256) {
        int c = cnt[i];
        base[i] = (c > 0) ? atomicAdd(&gcur[i], c) : 0;
        cnt[i] = 0;
    }
    __syncthreads();
#pragma unroll
    for (int k = 0; k < EPB / 256; k++) {
        int e = e0 + k * 256 + t;
        if (e < N_EDGES) {
            int d = dst[e];
            int b = d >> 8;
            int p = atomicAdd(&cnt[b], 1);
            bin[(size_t)b * BIN_CAP + base[b] + p] = ((unsigned)src[e] << 8) | (unsigned)(d & 255);
        }
    }
}

// ---------------- phase B1: per-bucket degree count + dinv + block sum ----------------

__global__ __launch_bounds__(256) void k_degBf(const int* __restrict__ gcur,
                                               const unsigned* __restrict__ bin,
                                               int* __restrict__ degcnt,
                                               float* __restrict__ dinv,
                                               int* __restrict__ bsum) {
    __shared__ int cnt[256];
    int b = blockIdx.x, t = threadIdx.x;
    cnt[t] = 0;
    __syncthreads();
    int n = gcur[b];
    const unsigned* seg = bin + (size_t)b * BIN_CAP;
    for (int i = t; i < n; i += 256) atomicAdd(&cnt[seg[i] & 255u], 1);
    __syncthreads();
    int c = cnt[t];
    int node = b * 256 + t;
    if (node < N_NODES) {
        degcnt[node] = c;
        dinv[node] = rsqrtf((float)c + 1.0f);
    }
    __syncthreads();
    for (int o = 128; o > 0; o >>= 1) {
        if (t < o) cnt[t] += cnt[t + o];
        __syncthreads();
    }
    if (t == 0) bsum[b] = cnt[0];
}

// ---------------- exclusive scan of bsum -> bofs (one 512-thread block) ----------------

__global__ __launch_bounds__(512) void k_scanb(const int* __restrict__ bsum,
                                               int* __restrict__ bofs) {
    __shared__ int s[512];
    int t = threadIdx.x;
    int v = (t < NBUCKETS) ? bsum[t] : 0;
    s[t] = v;
    __syncthreads();
    for (int o = 1; o < 512; o <<= 1) {
        int u = (t >= o) ? s[t - o] : 0;
        __syncthreads();
        s[t] += u;
        __syncthreads();
    }
    if (t < NBUCKETS) bofs[t] = s[t] - v;
}

// ---------------- phase B2: fused rowstart + CSR fill (int2 {src, w}); zeroes gt_sum ----------------

__global__ __launch_bounds__(256) void k_rowfill(const int* __restrict__ degcnt,
                                                 const int* __restrict__ bofs,
                                                 const int* __restrict__ gcur,
                                                 const unsigned* __restrict__ bin,
                                                 const float* __restrict__ dinv,
                                                 int* __restrict__ row_start,
                                                 int2* __restrict__ csre,
                                                 float* __restrict__ gt_sum) {
    __shared__ int sc[256];
    __shared__ int rsl[256];
    __shared__ int cnt[256];
    __shared__ float dl[256];
    int b = blockIdx.x, t = threadIdx.x;
    // fused zeroing of gt_sum (8192 floats) by first 32 blocks
    if (b < 32) gt_sum[b * 256 + t] = 0.0f;
    int node = b * 256 + t;
    int v = (node < N_NODES) ? degcnt[node] : 0;
    sc[t] = v;
    __syncthreads();
    for (int o = 1; o < 256; o <<= 1) {
        int u = (t >= o) ? sc[t - o] : 0;
        __syncthreads();
        sc[t] += u;
        __syncthreads();
    }
    int rs = bofs[b] + sc[t] - v;  // exclusive
    if (node < N_NODES) row_start[node] = rs;
    rsl[t] = rs;
    cnt[t] = 0;
    dl[t] = rsqrtf((float)v + 1.0f);
    __syncthreads();
    int n = gcur[b];
    const unsigned* seg = bin + (size_t)b * BIN_CAP;
    for (int i = t; i < n; i += 256) {
        unsigned e = seg[i];
        int dlidx = (int)(e & 255u);
        int s = (int)(e >> 8);
        int pos = rsl[dlidx] + atomicAdd(&cnt[dlidx], 1);
        csre[pos] = make_int2(s, __float_as_int(dinv[s] * dl[dlidx]));
    }
}

// ---------------- fused: pack x[:, :64] to bf16 + graph feature pooling ----------------

__global__ __launch_bounds__(256) void k_packstat(const float* __restrict__ x,
                                                  const int* __restrict__ batch,
                                                  ushort* __restrict__ xb,
                                                  float* __restrict__ gt_sum) {
    int t = threadIdx.x;
    int i0 = blockIdx.x * 64;
    for (int idx = t; idx < 64 * 32; idx += 256) {
        int node = i0 + (idx >> 5);
        if (node < N_NODES) {
            int c2 = idx & 31;
            float2 v = *(const float2*)&x[(size_t)node * 80 + c2 * 2];
            __hip_bfloat16 lo = __float2bfloat16(v.x);
            __hip_bfloat16 hi = __float2bfloat16(v.y);
            ushort2 pv = make_ushort2(*(ushort*)&lo, *(ushort*)&hi);
            ((ushort2*)xb)[(size_t)node * 32 + c2] = pv;
        }
    }
    int c = t & 15, sub = t >> 4;  // 16 subs x 16 channels
    int iend = min(i0 + 64, N_NODES);
    float acc = 0.0f;
    int g = -1;
    for (int i = i0 + sub; i < iend; i += 16) {
        int bi = batch[i];
        if (bi != g) {
            if (g >= 0) atomicAdd(&gt_sum[g * GRAPH_DIM + c], acc);
            acc = 0.0f; g = bi;
        }
        acc += x[(size_t)i * 80 + NODE_DIM + c];
    }
    if (g >= 0) atomicAdd(&gt_sum[g * GRAPH_DIM + c], acc);
}

// ---------------- gather1: z = A_hat * x64; half-wave per node, 4B/lane ----------------

__global__ __launch_bounds__(256) void k_gather1(const int2* __restrict__ csre,
                                                 const int* __restrict__ row_start,
                                                 const float* __restrict__ dinv,
                                                 const unsigned* __restrict__ xb32,
                                                 float2* __restrict__ z2) {
    int w = threadIdx.x >> 6;
    int half = (threadIdx.x >> 5) & 1;
    int l = threadIdx.x & 31;
    int node = blockIdx.x * 8 + w * 2 + half;
    int rs = row_start[node];
    int re = (node == N_NODES - 1) ? N_EDGES : row_start[node + 1];
    float2 a0 = {0.f, 0.f}, a1 = {0.f, 0.f}, a2 = {0.f, 0.f}, a3 = {0.f, 0.f};
    int k = rs;
    for (; k + 4 <= re; k += 4) {
        int2 e0 = csre[k], e1 = csre[k + 1], e2 = csre[k + 2], e3 = csre[k + 3];
        unsigned u0 = xb32[(size_t)e0.x * 32 + l];
        unsigned u1 = xb32[(size_t)e1.x * 32 + l];
        unsigned u2 = xb32[(size_t)e2.x * 32 + l];
        unsigned u3 = xb32[(size_t)e3.x * 32 + l];
        float w0 = __int_as_float(e0.y), w1 = __int_as_float(e1.y);
        float w2 = __int_as_float(e2.y), w3 = __int_as_float(e3.y);
        a0.x += w0 * bflo(u0); a0.y += w0 * bfhi(u0);
        a1.x += w1 * bflo(u1); a1.y += w1 * bfhi(u1);
        a2.x += w2 * bflo(u2); a2.y += w2 * bfhi(u2);
        a3.x += w3 * bflo(u3); a3.y += w3 * bfhi(u3);
    }
    if (k + 2 <= re) {
        int2 e0 = csre[k], e1 = csre[k + 1];
        unsigned u0 = xb32[(size_t)e0.x * 32 + l];
        unsigned u1 = xb32[(size_t)e1.x * 32 + l];
        float w0 = __int_as_float(e0.y), w1 = __int_as_float(e1.y);
        a0.x += w0 * bflo(u0); a0.y += w0 * bfhi(u0);
        a1.x += w1 * bflo(u1); a1.y += w1 * bfhi(u1);
        k += 2;
    }
    if (k < re) {
        int2 e0 = csre[k];
        unsigned u0 = xb32[(size_t)e0.x * 32 + l];
        float w0 = __int_as_float(e0.y);
        a0.x += w0 * bflo(u0); a0.y += w0 * bfhi(u0);
    }
    float d = dinv[node];
    unsigned us = xb32[(size_t)node * 32 + l];
    float2 r;
    r.x = a0.x + a1.x + a2.x + a3.x + d * d * bflo(us);
    r.y = a0.y + a1.y + a2.y + a3.y + d * d * bfhi(us);
    z2[(size_t)node * 32 + l] = r;
}

// ---------------- GEMM: h1(bf16) = relu(z @ W1 + b1); zeroes gsum2 ----------------

__global__ __launch_bounds__(128) void k_gemm64(const float* __restrict__ A,
                                                const float* __restrict__ W,
                                                const float* __restrict__ bias,
                                                ushort* __restrict__ C, int nrows,
                                                float* __restrict__ gsum2) {
    const int TM = 8, K = 64;
    __shared__ float As[TM][K];
    if (blockIdx.x < 512) gsum2[blockIdx.x * 128 + threadIdx.x] = 0.0f;
    int row0 = blockIdx.x * TM;
    int j = threadIdx.x;  // 0..127
    for (int idx = threadIdx.x; idx < TM * K; idx += 128) {
        int m = idx / K, k = idx % K;
        int r = row0 + m;
        As[m][k] = (r < nrows) ? A[(size_t)r * K + k] : 0.0f;
    }
    __syncthreads();
    float acc[TM];
#pragma unroll
    for (int m = 0; m < TM; m++) acc[m] = 0.0f;
    for (int k = 0; k < K; k++) {
        float w = W[k * 128 + j];
#pragma unroll
        for (int m = 0; m < TM; m++) acc[m] += As[m][k] * w;
    }
    float b = bias[j];
#pragma unroll
    for (int m = 0; m < TM; m++) {
        int r = row0 + m;
        if (r < nrows) {
            float v = fmaxf(acc[m] + b, 0.0f);
            __hip_bfloat16 hv = __float2bfloat16(v);
            C[(size_t)r * 128 + j] = *(ushort*)&hv;
        }
    }
}

// ---------------- gather2: half-wave per node, 8B/lane (4 ch), fused mean-pool ----------------

__global__ __launch_bounds__(256) void k_gather2(const int2* __restrict__ csre,
                                                 const int* __restrict__ row_start,
                                                 const float* __restrict__ dinv,
                                                 const uint2* __restrict__ h2,
                                                 const int* __restrict__ batch,
                                                 float* __restrict__ gsum2) {
    __shared__ float4 red[8][32];
    int w = threadIdx.x >> 6;
    int half = (threadIdx.x >> 5) & 1;
    int l = threadIdx.x & 31;
    int slot = w * 2 + half;
    int node = blockIdx.x * 8 + slot;
    int rs = row_start[node];
    int re = (node == N_NODES - 1) ? N_EDGES : row_start[node + 1];
    float4 a0 = {0,0,0,0}, a1 = {0,0,0,0}, a2 = {0,0,0,0}, a3 = {0,0,0,0};
#define FMA4(acc_, w_, u_) { acc_.x += (w_) * bflo((u_).x); acc_.y += (w_) * bfhi((u_).x); \
                             acc_.z += (w_) * bflo((u_).y); acc_.w += (w_) * bfhi((u_).y); }
    int k = rs;
    for (; k + 4 <= re; k += 4) {
        int2 e0 = csre[k], e1 = csre[k + 1], e2 = csre[k + 2], e3 = csre[k + 3];
        uint2 u0 = h2[(size_t)e0.x * 32 + l];
        uint2 u1 = h2[(size_t)e1.x * 32 + l];
        uint2 u2 = h2[(size_t)e2.x * 32 + l];
        uint2 u3 = h2[(size_t)e3.x * 32 + l];
        float w0 = __int_as_float(e0.y), w1 = __int_as_float(e1.y);
        float w2 = __int_as_float(e2.y), w3 = __int_as_float(e3.y);
        FMA4(a0, w0, u0); FMA4(a1, w1, u1); FMA4(a2, w2, u2); FMA4(a3, w3, u3);
    }
    if (k + 2 <= re) {
        int2 e0 = csre[k], e1 = csre[k + 1];
        uint2 u0 = h2[(size_t)e0.x * 32 + l];
        uint2 u1 = h2[(size_t)e1.x * 32 + l];
        float w0 = __int_as_float(e0.y), w1 = __int_as_float(e1.y);
        FMA4(a0, w0, u0); FMA4(a1, w1, u1);
        k += 2;
    }
    if (k < re) {
        int2 e0 = csre[k];
        uint2 u0 = h2[(size_t)e0.x * 32 + l];
        float w0 = __int_as_float(e0.y);
        FMA4(a0, w0, u0);
    }
#undef FMA4
    float d = dinv[node];
    float dd = d * d;
    uint2 us = h2[(size_t)node * 32 + l];
    float4 r;
    r.x = a0.x + a1.x + a2.x + a3.x + dd * bflo(us.x);
    r.y = a0.y + a1.y + a2.y + a3.y + dd * bfhi(us.x);
    r.z = a0.z + a1.z + a2.z + a3.z + dd * bflo(us.y);
    r.w = a0.w + a1.w + a2.w + a3.w + dd * bfhi(us.y);
    red[slot][l] = r;
    __syncthreads();
    int base8 = blockIdx.x * 8;
    int g0 = batch[base8];
    int g7 = batch[base8 + 7];
    if (g0 == g7) {
        if (threadIdx.x < 32) {
            float4 s = {0,0,0,0};
#pragma unroll
            for (int q = 0; q < 8; q++) {
                float4 v = red[q][threadIdx.x];
                s.x += v.x; s.y += v.y; s.z += v.z; s.w += v.w;
            }
            atomicAdd(&gsum2[g0 * 128 + threadIdx.x * 4 + 0], s.x);
            atomicAdd(&gsum2[g0 * 128 + threadIdx.x * 4 + 1], s.y);
            atomicAdd(&gsum2[g0 * 128 + threadIdx.x * 4 + 2], s.z);
            atomicAdd(&gsum2[g0 * 128 + threadIdx.x * 4 + 3], s.w);
        }
    } else {
        int g = batch[node];
        atomicAdd(&gsum2[g * 128 + l * 4 + 0], r.x);
        atomicAdd(&gsum2[g * 128 + l * 4 + 1], r.y);
        atomicAdd(&gsum2[g * 128 + l * 4 + 2], r.z);
        atomicAdd(&gsum2[g * 128 + l * 4 + 3], r.w);
    }
}

// ---------------- final: gcnt (binary search) + z = mean2 @ W2 + b2 ; MLP ----------------

__global__ __launch_bounds__(128) void k_mlp(const float* __restrict__ gsum2,
                                             const float* __restrict__ gt_sum,
                                             const int* __restrict__ batch,
                                             const float* __restrict__ W2,
                                             const float* __restrict__ b2,
                                             const float* __restrict__ Wm1,
                                             const float* __restrict__ bm1,
                                             const float* __restrict__ Wm2,
                                             const float* __restrict__ bm2,
                                             float* __restrict__ out) {
    __shared__ float srow[HIDDEN];
    __shared__ float g144[HIDDEN + GRAPH_DIM];
    __shared__ float sm[HIDDEN];
    __shared__ int cnt_sh;
    int b = blockIdx.x;
    int j = threadIdx.x;  // 0..127
    float raw = gsum2[b * 128 + j];
    float gtraw = (j < GRAPH_DIM) ? gt_sum[b * GRAPH_DIM + j] : 0.0f;
    if (j == 0) {
        int lo = 0, hi = N_NODES;
        while (lo < hi) { int m = (lo + hi) >> 1; if (batch[m] < b) lo = m + 1; else hi = m; }
        int a = lo;
        lo = 0; hi = N_NODES;
        while (lo < hi) { int m = (lo + hi) >> 1; if (batch[m] < b + 1) lo = m + 1; else hi = m; }
        cnt_sh = lo - a;
    }
    __syncthreads();
    float inv = 1.0f / fmaxf((float)cnt_sh, 1.0f);
    srow[j] = raw * inv;
    if (j < GRAPH_DIM) g144[128 + j] = gtraw * inv;
    __syncthreads();
    float z = b2[j];
    for (int k = 0; k < 128; k++) z += srow[k] * W2[k * 128 + j];
    g144[j] = z;
    __syncthreads();
    float acc = bm1[j];
    for (int k = 0; k < HIDDEN + GRAPH_DIM; k++) acc += g144[k] * Wm1[k * 128 + j];
    sm[j] = fmaxf(acc, 0.0f);
    __syncthreads();
    if (j < OUT_DIM) {
        float o = bm2[j];
        for (int k = 0; k < 128; k++) o += sm[k] * Wm2[k * OUT_DIM + j];
        out[b * OUT_DIM + j] = o;
    }
}

extern "C" void kernel_launch(void* const* d_in, const int* in_sizes, int n_in,
                              void* d_out, int out_size, void* d_ws, size_t ws_size,
                              hipStream_t stream) {
    const float* x    = (const float*)d_in[0];
    const int*   edge = (const int*)d_in[1];
    const int*   src  = edge;
    const int*   dst  = edge + N_EDGES;
    const int*   batch= (const int*)d_in[2];
    const float* W1   = (const float*)d_in[3];
    const float* b1   = (const float*)d_in[4];
    const float* W2   = (const float*)d_in[5];
    const float* b2   = (const float*)d_in[6];
    const float* Wm1  = (const float*)d_in[7];
    const float* bm1  = (const float*)d_in[8];
    const float* Wm2  = (const float*)d_in[9];
    const float* bm2  = (const float*)d_in[10];
    float* out = (float*)d_out;

    // workspace layout (~91 MB)
    char* ws = (char*)d_ws;
    char* p = ws;
    unsigned* bin   = (unsigned*)p;  p += (size_t)NBUCKETS * BIN_CAP * 4;   // 12.8 MB
    int2*  csre     = (int2*)p;      p += (size_t)N_EDGES * 8;              // 12.8 MB
    float* A        = (float*)p;     p += (size_t)N_NODES * 64 * 4;         // z1 25.6 MB
    ushort* h1b     = (ushort*)p;    p += (size_t)N_NODES * 128 * 2;        // h1 bf16 25.6 MB
    ushort* xb      = (ushort*)p;    p += (size_t)N_NODES * 64 * 2;         // x bf16 12.8 MB
    int*   degcnt   = (int*)p;       p += (size_t)NBUCKETS * 256 * 4;
    int*   row_start= (int*)p;       p += (size_t)N_NODES * 4;
    float* dinv     = (float*)p;     p += (size_t)N_NODES * 4;
    int*   gcur     = (int*)p;       p += (size_t)NBUCKETS * 4;
    int*   bsum     = (int*)p;       p += 512 * 4;
    int*   bofs     = (int*)p;       p += 512 * 4;
    float* gt_sum   = (float*)p;     p += (size_t)N_GRAPHS * GRAPH_DIM * 4;
    float* gsum2    = (float*)p;     p += (size_t)N_GRAPHS * 128 * 4;

    hipMemsetAsync(gcur, 0, (size_t)NBUCKETS * 4, stream);

    // CSR build
    k_binplace<<<(N_EDGES + EPB - 1) / EPB, 256, 0, stream>>>(src, dst, gcur, bin);
    k_degBf<<<NBUCKETS, 256, 0, stream>>>(gcur, bin, degcnt, dinv, bsum);
    k_scanb<<<1, 512, 0, stream>>>(bsum, bofs);
    k_rowfill<<<NBUCKETS, 256, 0, stream>>>(degcnt, bofs, gcur, bin, dinv, row_start, csre, gt_sum);

    // bf16 pack + graph stats
    k_packstat<<<(N_NODES + 63) / 64, 256, 0, stream>>>(x, batch, xb, gt_sum);

    // conv1: z1 = A_hat * x64 ; h1 = relu(z1 @ W1 + b1) (bf16)
    k_gather1<<<N_NODES / 8, 256, 0, stream>>>(csre, row_start, dinv, (const unsigned*)xb, (float2*)A);
    k_gemm64<<<(N_NODES + 7) / 8, 128, 0, stream>>>(A, W1, b1, h1b, N_NODES, gsum2);

    // conv2 pooled: gsum2[g] = sum_{node in g} (A_hat h1)[node]
    k_gather2<<<N_NODES / 8, 256, 0, stream>>>(csre, row_start, dinv,
                                               (const uint2*)h1b, batch, gsum2);

    // final: gcnt + z = (gsum2/cnt) @ W2 + b2 ; MLP
    k_mlp<<<N_GRAPHS, 128, 0, stream>>>(gsum2, gt_sum, batch, W2, b2, Wm1, bm1, Wm2, bm2, out);
}

// Round 7
// 248.236 us; speedup vs baseline: 7.2241x; 1.0397x over previous
//
#include <hip/hip_runtime.h>
#include <hip/hip_bf16.h>

#define N_NODES 100000
#define N_EDGES 1600000
#define N_GRAPHS 512
#define NODE_DIM 64
#define GRAPH_DIM 16
#define HIDDEN 128
#define OUT_DIM 8

#define NBUCKETS 391      // ceil(N_NODES/256)
#define BIN_CAP 8192      // per-bucket bin capacity (avg 4092)
#define EPB 4096          // edges per binning block

__device__ __forceinline__ float bflo(unsigned u) { return __uint_as_float(u << 16); }
__device__ __forceinline__ float bfhi(unsigned u) { return __uint_as_float(u & 0xffff0000u); }

// ---------------- phase A: bin edges by dst>>8; entry = (src<<8)|(dst&255) ----------------

__global__ __launch_bounds__(256) void k_binplace(const int* __restrict__ src,
                                                  const int* __restrict__ dst,
                                                  int* __restrict__ gcur,
                                                  unsigned* __restrict__ bin) {
    __shared__ int cnt[NBUCKETS];
    __shared__ int base[NBUCKETS];
    int t = threadIdx.x;
    for (int i = t; i < NBUCKETS; i += 256) cnt[i] = 0;
    __syncthreads();
    int e0 = blockIdx.x * EPB;
#pragma unroll
    for (int k = 0; k < EPB / 256; k++) {
        int e = e0 + k * 256 + t;
        if (e < N_EDGES) atomicAdd(&cnt[dst[e] >> 8], 1);
    }
    __syncthreads();
    for (int i = t; i < NBUCKETS; i += 256) {
        int c = cnt[i];
        base[i] = (c > 0) ? atomicAdd(&gcur[i], c) : 0;
        cnt[i] = 0;
    }
    __syncthreads();
#pragma unroll
    for (int k = 0; k < EPB / 256; k++) {
        int e = e0 + k * 256 + t;
        if (e < N_EDGES) {
            int d = dst[e];
            int b = d >> 8;
            int p = atomicAdd(&cnt[b], 1);
            bin[(size_t)b * BIN_CAP + base[b] + p] = ((unsigned)src[e] << 8) | (unsigned)(d & 255);
        }
    }
}

// ---------------- phase B1: per-bucket degree count + dinv + block sum ----------------

__global__ __launch_bounds__(256) void k_degBf(const int* __restrict__ gcur,
                                               const unsigned* __restrict__ bin,
                                               int* __restrict__ degcnt,
                                               float* __restrict__ dinv,
                                               int* __restrict__ bsum) {
    __shared__ int cnt[256];
    int b = blockIdx.x, t = threadIdx.x;
    cnt[t] = 0;
    __syncthreads();
    int n = gcur[b];
    const unsigned* seg = bin + (size_t)b * BIN_CAP;
    for (int i = t; i < n; i += 256) atomicAdd(&cnt[seg[i] & 255u], 1);
    __syncthreads();
    int c = cnt[t];
    int node = b * 256 + t;
    if (node < N_NODES) {
        degcnt[node] = c;
        dinv[node] = rsqrtf((float)c + 1.0f);
    }
    __syncthreads();
    for (int o = 128; o > 0; o >>= 1) {
        if (t < o) cnt[t] += cnt[t + o];
        __syncthreads();
    }
    if (t == 0) bsum[b] = cnt[0];
}

// ---------------- exclusive scan of bsum -> bofs (one 512-thread block) ----------------

__global__ __launch_bounds__(512) void k_scanb(const int* __restrict__ bsum,
                                               int* __restrict__ bofs) {
    __shared__ int s[512];
    int t = threadIdx.x;
    int v = (t < NBUCKETS) ? bsum[t] : 0;
    s[t] = v;
    __syncthreads();
    for (int o = 1; o < 512; o <<= 1) {
        int u = (t >= o) ? s[t - o] : 0;
        __syncthreads();
        s[t] += u;
        __syncthreads();
    }
    if (t < NBUCKETS) bofs[t] = s[t] - v;
}

// ---------------- phase B2: fused rowstart + CSR fill (int2 {src, w}); zeroes gt_sum ----------------

__global__ __launch_bounds__(256) void k_rowfill(const int* __restrict__ degcnt,
                                                 const int* __restrict__ bofs,
                                                 const int* __restrict__ gcur,
                                                 const unsigned* __restrict__ bin,
                                                 const float* __restrict__ dinv,
                                                 int* __restrict__ row_start,
                                                 int2* __restrict__ csre,
                                                 float* __restrict__ gt_sum) {
    __shared__ int sc[256];
    __shared__ int rsl[256];
    __shared__ int cnt[256];
    __shared__ float dl[256];
    int b = blockIdx.x, t = threadIdx.x;
    if (b < 32) gt_sum[b * 256 + t] = 0.0f;
    int node = b * 256 + t;
    int v = (node < N_NODES) ? degcnt[node] : 0;
    sc[t] = v;
    __syncthreads();
    for (int o = 1; o < 256; o <<= 1) {
        int u = (t >= o) ? sc[t - o] : 0;
        __syncthreads();
        sc[t] += u;
        __syncthreads();
    }
    int rs = bofs[b] + sc[t] - v;  // exclusive
    if (node < N_NODES) row_start[node] = rs;
    rsl[t] = rs;
    cnt[t] = 0;
    dl[t] = rsqrtf((float)v + 1.0f);
    __syncthreads();
    int n = gcur[b];
    const unsigned* seg = bin + (size_t)b * BIN_CAP;
    for (int i = t; i < n; i += 256) {
        unsigned e = seg[i];
        int dlidx = (int)(e & 255u);
        int s = (int)(e >> 8);
        int pos = rsl[dlidx] + atomicAdd(&cnt[dlidx], 1);
        csre[pos] = make_int2(s, __float_as_int(dinv[s] * dl[dlidx]));
    }
}

// ---------------- fused: pack x[:, :64] to bf16 + graph feature pooling ----------------

__global__ __launch_bounds__(256) void k_packstat(const float* __restrict__ x,
                                                  const int* __restrict__ batch,
                                                  ushort* __restrict__ xb,
                                                  float* __restrict__ gt_sum) {
    int t = threadIdx.x;
    int i0 = blockIdx.x * 64;
    for (int idx = t; idx < 64 * 32; idx += 256) {
        int node = i0 + (idx >> 5);
        if (node < N_NODES) {
            int c2 = idx & 31;
            float2 v = *(const float2*)&x[(size_t)node * 80 + c2 * 2];
            __hip_bfloat16 lo = __float2bfloat16(v.x);
            __hip_bfloat16 hi = __float2bfloat16(v.y);
            ushort2 pv = make_ushort2(*(ushort*)&lo, *(ushort*)&hi);
            ((ushort2*)xb)[(size_t)node * 32 + c2] = pv;
        }
    }
    int c = t & 15, sub = t >> 4;  // 16 subs x 16 channels
    int iend = min(i0 + 64, N_NODES);
    float acc = 0.0f;
    int g = -1;
    for (int i = i0 + sub; i < iend; i += 16) {
        int bi = batch[i];
        if (bi != g) {
            if (g >= 0) atomicAdd(&gt_sum[g * GRAPH_DIM + c], acc);
            acc = 0.0f; g = bi;
        }
        acc += x[(size_t)i * 80 + NODE_DIM + c];
    }
    if (g >= 0) atomicAdd(&gt_sum[g * GRAPH_DIM + c], acc);
}

// ---------------- fused conv1: gather (A_hat x64) into LDS + GEMM -> h1 bf16; zeroes gsum2 ----

#define LDX(s_) __uint_as_float((unsigned)xb[(size_t)(s_)*64 + lane] << 16)

__global__ __launch_bounds__(256) void k_conv1(const int2* __restrict__ csre,
                                               const int* __restrict__ row_start,
                                               const float* __restrict__ dinv,
                                               const ushort* __restrict__ xb,
                                               const float* __restrict__ W,
                                               const float* __restrict__ bias,
                                               ushort* __restrict__ C,
                                               float* __restrict__ gsum2) {
    __shared__ float zs[8][64];
    int t = threadIdx.x;
    if (blockIdx.x < 256) gsum2[blockIdx.x * 256 + t] = 0.0f;
    int w = t >> 6, lane = t & 63;
    int nA = blockIdx.x * 8 + w * 2;
    int nB = nA + 1;
    int rsA = row_start[nA], reA = (nA == N_NODES - 1) ? N_EDGES : row_start[nA + 1];
    int rsB = row_start[nB], reB = (nB == N_NODES - 1) ? N_EDGES : row_start[nB + 1];
    float aA0 = 0.f, aA1 = 0.f, aA2 = 0.f, aA3 = 0.f;
    float aB0 = 0.f, aB1 = 0.f, aB2 = 0.f, aB3 = 0.f;
    int kA = rsA, kB = rsB;
    while (kA + 4 <= reA && kB + 4 <= reB) {
        int2 eA0 = csre[kA], eA1 = csre[kA + 1], eA2 = csre[kA + 2], eA3 = csre[kA + 3];
        int2 eB0 = csre[kB], eB1 = csre[kB + 1], eB2 = csre[kB + 2], eB3 = csre[kB + 3];
        float vA0 = LDX(eA0.x), vA1 = LDX(eA1.x), vA2 = LDX(eA2.x), vA3 = LDX(eA3.x);
        float vB0 = LDX(eB0.x), vB1 = LDX(eB1.x), vB2 = LDX(eB2.x), vB3 = LDX(eB3.x);
        aA0 += __int_as_float(eA0.y) * vA0; aA1 += __int_as_float(eA1.y) * vA1;
        aA2 += __int_as_float(eA2.y) * vA2; aA3 += __int_as_float(eA3.y) * vA3;
        aB0 += __int_as_float(eB0.y) * vB0; aB1 += __int_as_float(eB1.y) * vB1;
        aB2 += __int_as_float(eB2.y) * vB2; aB3 += __int_as_float(eB3.y) * vB3;
        kA += 4; kB += 4;
    }
    while (kA + 4 <= reA) {
        int2 e0 = csre[kA], e1 = csre[kA + 1], e2 = csre[kA + 2], e3 = csre[kA + 3];
        float v0 = LDX(e0.x), v1 = LDX(e1.x), v2 = LDX(e2.x), v3 = LDX(e3.x);
        aA0 += __int_as_float(e0.y) * v0; aA1 += __int_as_float(e1.y) * v1;
        aA2 += __int_as_float(e2.y) * v2; aA3 += __int_as_float(e3.y) * v3;
        kA += 4;
    }
    while (kB + 4 <= reB) {
        int2 e0 = csre[kB], e1 = csre[kB + 1], e2 = csre[kB + 2], e3 = csre[kB + 3];
        float v0 = LDX(e0.x), v1 = LDX(e1.x), v2 = LDX(e2.x), v3 = LDX(e3.x);
        aB0 += __int_as_float(e0.y) * v0; aB1 += __int_as_float(e1.y) * v1;
        aB2 += __int_as_float(e2.y) * v2; aB3 += __int_as_float(e3.y) * v3;
        kB += 4;
    }
    while (kA < reA && kB < reB) {
        int2 eA = csre[kA]; int2 eB = csre[kB];
        aA0 += __int_as_float(eA.y) * LDX(eA.x);
        aB0 += __int_as_float(eB.y) * LDX(eB.x);
        kA++; kB++;
    }
    while (kA < reA) { int2 e = csre[kA]; aA0 += __int_as_float(e.y) * LDX(e.x); kA++; }
    while (kB < reB) { int2 e = csre[kB]; aB0 += __int_as_float(e.y) * LDX(e.x); kB++; }
    float dA = dinv[nA], dB = dinv[nB];
    zs[w * 2][lane]     = aA0 + aA1 + aA2 + aA3 + dA * dA * LDX(nA);
    zs[w * 2 + 1][lane] = aB0 + aB1 + aB2 + aB3 + dB * dB * LDX(nB);
    __syncthreads();
    // GEMM phase: threads 0..127, TM=8 rows from LDS
    if (t < 128) {
        int j = t;
        float acc[8];
#pragma unroll
        for (int m = 0; m < 8; m++) acc[m] = 0.0f;
        for (int k = 0; k < 64; k++) {
            float wv = W[k * 128 + j];
#pragma unroll
            for (int m = 0; m < 8; m++) acc[m] += zs[m][k] * wv;
        }
        float b = bias[j];
        size_t row0 = (size_t)blockIdx.x * 8;
#pragma unroll
        for (int m = 0; m < 8; m++) {
            float v = fmaxf(acc[m] + b, 0.0f);
            __hip_bfloat16 hv = __float2bfloat16(v);
            C[(row0 + m) * 128 + j] = *(ushort*)&hv;
        }
    }
}

// ---------------- gather2 (bf16 h1, whole-wave, 2 nodes/wave) + fused mean-pool ----------------

__global__ __launch_bounds__(256) void k_gather2(const int2* __restrict__ csre,
                                                 const int* __restrict__ row_start,
                                                 const float* __restrict__ dinv,
                                                 const unsigned* __restrict__ h,
                                                 const int* __restrict__ batch,
                                                 float* __restrict__ gsum2) {
    __shared__ float2 red[8][64];
    int w = threadIdx.x >> 6, lane = threadIdx.x & 63;
    int nA = blockIdx.x * 8 + w * 2;
    int nB = nA + 1;
    int rsA = row_start[nA], reA = (nA == N_NODES - 1) ? N_EDGES : row_start[nA + 1];
    int rsB = row_start[nB], reB = (nB == N_NODES - 1) ? N_EDGES : row_start[nB + 1];
    float2 aA0 = {0.f,0.f}, aA1 = {0.f,0.f}, aA2 = {0.f,0.f}, aA3 = {0.f,0.f};
    float2 aB0 = {0.f,0.f}, aB1 = {0.f,0.f}, aB2 = {0.f,0.f}, aB3 = {0.f,0.f};
    int kA = rsA, kB = rsB;
#define FMA2(acc_, wbits_, u_) { float w_ = __int_as_float(wbits_); \
                             acc_.x += w_ * bflo(u_); acc_.y += w_ * bfhi(u_); }
    while (kA + 4 <= reA && kB + 4 <= reB) {
        int2 eA0 = csre[kA], eA1 = csre[kA + 1], eA2 = csre[kA + 2], eA3 = csre[kA + 3];
        int2 eB0 = csre[kB], eB1 = csre[kB + 1], eB2 = csre[kB + 2], eB3 = csre[kB + 3];
        unsigned uA0 = h[(size_t)eA0.x * 64 + lane], uA1 = h[(size_t)eA1.x * 64 + lane];
        unsigned uA2 = h[(size_t)eA2.x * 64 + lane], uA3 = h[(size_t)eA3.x * 64 + lane];
        unsigned uB0 = h[(size_t)eB0.x * 64 + lane], uB1 = h[(size_t)eB1.x * 64 + lane];
        unsigned uB2 = h[(size_t)eB2.x * 64 + lane], uB3 = h[(size_t)eB3.x * 64 + lane];
        FMA2(aA0, eA0.y, uA0); FMA2(aA1, eA1.y, uA1); FMA2(aA2, eA2.y, uA2); FMA2(aA3, eA3.y, uA3);
        FMA2(aB0, eB0.y, uB0); FMA2(aB1, eB1.y, uB1); FMA2(aB2, eB2.y, uB2); FMA2(aB3, eB3.y, uB3);
        kA += 4; kB += 4;
    }
    while (kA + 4 <= reA) {
        int2 e0 = csre[kA], e1 = csre[kA + 1], e2 = csre[kA + 2], e3 = csre[kA + 3];
        unsigned u0 = h[(size_t)e0.x * 64 + lane], u1 = h[(size_t)e1.x * 64 + lane];
        unsigned u2 = h[(size_t)e2.x * 64 + lane], u3 = h[(size_t)e3.x * 64 + lane];
        FMA2(aA0, e0.y, u0); FMA2(aA1, e1.y, u1); FMA2(aA2, e2.y, u2); FMA2(aA3, e3.y, u3);
        kA += 4;
    }
    while (kB + 4 <= reB) {
        int2 e0 = csre[kB], e1 = csre[kB + 1], e2 = csre[kB + 2], e3 = csre[kB + 3];
        unsigned u0 = h[(size_t)e0.x * 64 + lane], u1 = h[(size_t)e1.x * 64 + lane];
        unsigned u2 = h[(size_t)e2.x * 64 + lane], u3 = h[(size_t)e3.x * 64 + lane];
        FMA2(aB0, e0.y, u0); FMA2(aB1, e1.y, u1); FMA2(aB2, e2.y, u2); FMA2(aB3, e3.y, u3);
        kB += 4;
    }
    while (kA < reA && kB < reB) {
        int2 eA = csre[kA]; int2 eB = csre[kB];
        unsigned uA = h[(size_t)eA.x * 64 + lane], uB = h[(size_t)eB.x * 64 + lane];
        FMA2(aA0, eA.y, uA); FMA2(aB0, eB.y, uB);
        kA++; kB++;
    }
    while (kA < reA) {
        int2 e = csre[kA]; unsigned u = h[(size_t)e.x * 64 + lane];
        FMA2(aA0, e.y, u); kA++;
    }
    while (kB < reB) {
        int2 e = csre[kB]; unsigned u = h[(size_t)e.x * 64 + lane];
        FMA2(aB0, e.y, u); kB++;
    }
#undef FMA2
    float dA = dinv[nA], dB = dinv[nB];
    unsigned usA = h[(size_t)nA * 64 + lane];
    unsigned usB = h[(size_t)nB * 64 + lane];
    float2 rA, rB;
    rA.x = aA0.x + aA1.x + aA2.x + aA3.x + dA * dA * bflo(usA);
    rA.y = aA0.y + aA1.y + aA2.y + aA3.y + dA * dA * bfhi(usA);
    rB.x = aB0.x + aB1.x + aB2.x + aB3.x + dB * dB * bflo(usB);
    rB.y = aB0.y + aB1.y + aB2.y + aB3.y + dB * dB * bfhi(usB);
    red[w * 2][lane] = rA;
    red[w * 2 + 1][lane] = rB;
    __syncthreads();
    int g0 = batch[blockIdx.x * 8];
    int g7 = batch[blockIdx.x * 8 + 7];
    if (g0 == g7) {
        if (w == 0) {
            float sx = 0.f, sy = 0.f;
#pragma unroll
            for (int q = 0; q < 8; q++) { sx += red[q][lane].x; sy += red[q][lane].y; }
            atomicAdd(&gsum2[g0 * 128 + 2 * lane], sx);
            atomicAdd(&gsum2[g0 * 128 + 2 * lane + 1], sy);
        }
    } else {
        int gA = batch[nA], gB = batch[nB];
        atomicAdd(&gsum2[gA * 128 + 2 * lane], rA.x);
        atomicAdd(&gsum2[gA * 128 + 2 * lane + 1], rA.y);
        atomicAdd(&gsum2[gB * 128 + 2 * lane], rB.x);
        atomicAdd(&gsum2[gB * 128 + 2 * lane + 1], rB.y);
    }
}

// ---------------- final: gcnt (binary search) + z = mean2 @ W2 + b2 ; MLP ----------------

__global__ __launch_bounds__(128) void k_mlp(const float* __restrict__ gsum2,
                                             const float* __restrict__ gt_sum,
                                             const int* __restrict__ batch,
                                             const float* __restrict__ W2,
                                             const float* __restrict__ b2,
                                             const float* __restrict__ Wm1,
                                             const float* __restrict__ bm1,
                                             const float* __restrict__ Wm2,
                                             const float* __restrict__ bm2,
                                             float* __restrict__ out) {
    __shared__ float srow[HIDDEN];
    __shared__ float g144[HIDDEN + GRAPH_DIM];
    __shared__ float sm[HIDDEN];
    __shared__ int cnt_sh;
    int b = blockIdx.x;
    int j = threadIdx.x;  // 0..127
    float raw = gsum2[b * 128 + j];
    float gtraw = (j < GRAPH_DIM) ? gt_sum[b * GRAPH_DIM + j] : 0.0f;
    if (j == 0) {
        int lo = 0, hi = N_NODES;
        while (lo < hi) { int m = (lo + hi) >> 1; if (batch[m] < b) lo = m + 1; else hi = m; }
        int a = lo;
        lo = 0; hi = N_NODES;
        while (lo < hi) { int m = (lo + hi) >> 1; if (batch[m] < b + 1) lo = m + 1; else hi = m; }
        cnt_sh = lo - a;
    }
    __syncthreads();
    float inv = 1.0f / fmaxf((float)cnt_sh, 1.0f);
    srow[j] = raw * inv;
    if (j < GRAPH_DIM) g144[128 + j] = gtraw * inv;
    __syncthreads();
    float z = b2[j];
    for (int k = 0; k < 128; k++) z += srow[k] * W2[k * 128 + j];
    g144[j] = z;
    __syncthreads();
    float acc = bm1[j];
    for (int k = 0; k < HIDDEN + GRAPH_DIM; k++) acc += g144[k] * Wm1[k * 128 + j];
    sm[j] = fmaxf(acc, 0.0f);
    __syncthreads();
    if (j < OUT_DIM) {
        float o = bm2[j];
        for (int k = 0; k < 128; k++) o += sm[k] * Wm2[k * OUT_DIM + j];
        out[b * OUT_DIM + j] = o;
    }
}

extern "C" void kernel_launch(void* const* d_in, const int* in_sizes, int n_in,
                              void* d_out, int out_size, void* d_ws, size_t ws_size,
                              hipStream_t stream) {
    const float* x    = (const float*)d_in[0];
    const int*   edge = (const int*)d_in[1];
    const int*   src  = edge;
    const int*   dst  = edge + N_EDGES;
    const int*   batch= (const int*)d_in[2];
    const float* W1   = (const float*)d_in[3];
    const float* b1   = (const float*)d_in[4];
    const float* W2   = (const float*)d_in[5];
    const float* b2   = (const float*)d_in[6];
    const float* Wm1  = (const float*)d_in[7];
    const float* bm1  = (const float*)d_in[8];
    const float* Wm2  = (const float*)d_in[9];
    const float* bm2  = (const float*)d_in[10];
    float* out = (float*)d_out;

    // workspace layout (~66 MB)
    char* ws = (char*)d_ws;
    char* p = ws;
    unsigned* bin   = (unsigned*)p;  p += (size_t)NBUCKETS * BIN_CAP * 4;   // 12.8 MB
    int2*  csre     = (int2*)p;      p += (size_t)N_EDGES * 8;              // 12.8 MB
    ushort* h1b     = (ushort*)p;    p += (size_t)N_NODES * 128 * 2;        // h1 bf16 25.6 MB
    ushort* xb      = (ushort*)p;    p += (size_t)N_NODES * 64 * 2;         // x bf16 12.8 MB
    int*   degcnt   = (int*)p;       p += (size_t)NBUCKETS * 256 * 4;
    int*   row_start= (int*)p;       p += (size_t)N_NODES * 4;
    float* dinv     = (float*)p;     p += (size_t)N_NODES * 4;
    int*   gcur     = (int*)p;       p += (size_t)NBUCKETS * 4;
    int*   bsum     = (int*)p;       p += 512 * 4;
    int*   bofs     = (int*)p;       p += 512 * 4;
    float* gt_sum   = (float*)p;     p += (size_t)N_GRAPHS * GRAPH_DIM * 4;
    float* gsum2    = (float*)p;     p += (size_t)N_GRAPHS * 128 * 4;

    hipMemsetAsync(gcur, 0, (size_t)NBUCKETS * 4, stream);

    // CSR build
    k_binplace<<<(N_EDGES + EPB - 1) / EPB, 256, 0, stream>>>(src, dst, gcur, bin);
    k_degBf<<<NBUCKETS, 256, 0, stream>>>(gcur, bin, degcnt, dinv, bsum);
    k_scanb<<<1, 512, 0, stream>>>(bsum, bofs);
    k_rowfill<<<NBUCKETS, 256, 0, stream>>>(degcnt, bofs, gcur, bin, dinv, row_start, csre, gt_sum);

    // bf16 pack + graph stats
    k_packstat<<<(N_NODES + 63) / 64, 256, 0, stream>>>(x, batch, xb, gt_sum);

    // conv1 fused: z1 = A_hat * x64 (LDS) ; h1 = relu(z1 @ W1 + b1) (bf16)
    k_conv1<<<N_NODES / 8, 256, 0, stream>>>(csre, row_start, dinv, xb, W1, b1, h1b, gsum2);

    // conv2 pooled: gsum2[g] = sum_{node in g} (A_hat h1)[node]
    k_gather2<<<N_NODES / 8, 256, 0, stream>>>(csre, row_start, dinv,
                                               (const unsigned*)h1b, batch, gsum2);

    // final: gcnt + z = (gsum2/cnt) @ W2 + b2 ; MLP
    k_mlp<<<N_GRAPHS, 128, 0, stream>>>(gsum2, gt_sum, batch, W2, b2, Wm1, bm1, Wm2, bm2, out);
}